// Round 3
// baseline (386.217 us; speedup 1.0000x reference)
//
#include <hip/hip_runtime.h>
#include <hip/hip_bf16.h>

// LogoAwareAttention: B=8, N=1024, C=768, H=12, Dh=64.
// Per-(b,h) scalar logit bias cancels in softmax -> dropped.
//
// R11 (evidence: R10's coarse 3-buf pipeline = T4 without T3 prereq ->
// regressed 53.5->88.5us exactly as regime-gate predicts. 2-phase 128^2 is
// at its structural ceiling for this shape):
//  * k_qkv: new 8-phase-style GEMM, BM=256 BN=288 BK=64, 512 thr (8 waves),
//    grid 32x8 = 256 blocks = EXACTLY 1/CU (zero tail quantization; a 256^2
//    port would be 288 blocks -> 2-round makespan, 1.78x waste).
//    136KB dynamic LDS dbuf; 4 phases/K-step {ds_read subtile || stage
//    half || setprio(1) 18xMFMA setprio(0) || s_barrier}; counted
//    vmcnt(4/5) at the 2 k-half boundaries, never 0 mid-loop (T3+T4+T5).
//    Barriers are inline-asm s_barrier WITH memory clobber so LDS reads
//    cannot hoist above them (builtin s_barrier is IntrNoMem -> hazard).
//    Q/K/V boundary falls on 16-col fragment edges: per-fragment MFMA
//    operand order chooses the store-friendly C layout (both mappings
//    refcheck-verified in R8/R10).
//  * k_proj: reverted to the known-good R8 2-buf structure.

typedef __bf16 b16x8 __attribute__((ext_vector_type(8)));
typedef float f32x4 __attribute__((ext_vector_type(4)));

__device__ __forceinline__ ushort f2b(float f) {
    union { float f; uint u; } v; v.f = f;
    uint u = v.u;
    u += 0x7fffu + ((u >> 16) & 1u);   // round-to-nearest-even
    return (ushort)(u >> 16);
}

__device__ __forceinline__ uint packbf(float a, float b) {
    union { float f; uint u; } ua, ub; ua.f = a; ub.f = b;
    return ((ua.u + 0x8000u) >> 16) | ((ub.u + 0x8000u) & 0xffff0000u);
}

// async 16B-per-lane global->LDS copy; lds dest = wave-uniform base + lane*16
__device__ __forceinline__ void async_cp16(const void* g, void* l) {
    __builtin_amdgcn_global_load_lds(
        (const __attribute__((address_space(1))) unsigned int*)g,
        (__attribute__((address_space(3))) unsigned int*)l, 16, 0, 0);
}

// ---------------- fused prep: x->bf16 | Wqkv^T | Wproj^T ----------------
// blocks [0,6144): conv;  [6144,6576): Wqkv transpose;  [6576,6720): Wproj.

__global__ __launch_bounds__(256)
void k_prep(const float* __restrict__ x, ushort* __restrict__ xb,
            const float* __restrict__ Wqkv, ushort* __restrict__ wqkvt,
            const float* __restrict__ Wproj, ushort* __restrict__ wprojt) {
    __shared__ ushort T[64][65];
    const int blk = blockIdx.x;
    const int t   = threadIdx.x;

    if (blk < 6144) {
        const int i = blk * 256 + t;
        const float4 v = reinterpret_cast<const float4*>(x)[i];
        ushort4 o;
        o.x = f2b(v.x); o.y = f2b(v.y); o.z = f2b(v.z); o.w = f2b(v.w);
        reinterpret_cast<ushort4*>(xb)[i] = o;
        return;
    }

    const bool isqkv = (blk < 6576);
    const int idx = isqkv ? (blk - 6144) : (blk - 6576);
    const int Nin = isqkv ? 2304 : 768;
    const float* W  = isqkv ? Wqkv : Wproj;
    ushort* Wt      = isqkv ? wqkvt : wprojt;
    const int k0 = (idx % 12) * 64;
    const int n0 = (idx / 12) * 64;
    const int r  = t >> 4, cg = (t & 15) * 4;
    #pragma unroll
    for (int rr = 0; rr < 64; rr += 16) {
        const float4 v = *reinterpret_cast<const float4*>(&W[(size_t)(k0 + r + rr) * Nin + n0 + cg]);
        T[r + rr][cg + 0] = f2b(v.x); T[r + rr][cg + 1] = f2b(v.y);
        T[r + rr][cg + 2] = f2b(v.z); T[r + rr][cg + 3] = f2b(v.w);
    }
    __syncthreads();
    #pragma unroll
    for (int rr = 0; rr < 64; rr += 16) {
        ushort4 o;
        o.x = T[cg + 0][r + rr]; o.y = T[cg + 1][r + rr];
        o.z = T[cg + 2][r + rr]; o.w = T[cg + 3][r + rr];
        *reinterpret_cast<ushort4*>(&Wt[(size_t)(n0 + r + rr) * 768 + k0 + cg]) = o;
    }
}

// ---------------- k_qkv: 256x288 tile, BK=64, 8 waves, 4-phase pipeline ----------

#define SBAR()   asm volatile("s_barrier" ::: "memory")
#define WAITV(n) asm volatile("s_waitcnt vmcnt(" #n ")" ::: "memory")

// LDS element offsets (ushort): A[buf] at buf*16384 (2x 256x64), B[buf] at
// 32768 + buf*18432 (2x 288x64); per k-half sections of [rows][32].
#define LDSA(buf, kh, ii) (*reinterpret_cast<const b16x8*>( \
    &lds[(buf) * 16384 + (kh) * 8192 + (wm * 64 + (ii) * 16 + m16) * 32 + q8]))
#define LDSB(buf, kh, jj) (*reinterpret_cast<const b16x8*>( \
    &lds[32768 + (buf) * 18432 + (kh) * 9216 + (wn * 144 + (jj) * 16 + m16) * 32 + q8]))

// stage one k-half of A (2 loads/thread) / B (2, +1 for waves 0-1)
#define STA(bufn, ktv, kh) { \
    async_cp16(&A[(size_t)(mbase + (2*w)*16 + srow) * 768 + (ktv) + (kh)*32 + ssub], \
               &lds[(bufn)*16384 + (kh)*8192 + (2*w)*512]); \
    async_cp16(&A[(size_t)(mbase + (2*w+1)*16 + srow) * 768 + (ktv) + (kh)*32 + ssub], \
               &lds[(bufn)*16384 + (kh)*8192 + (2*w+1)*512]); }
#define STB(bufn, ktv, kh) { \
    async_cp16(&Bt[(size_t)(nbase + (2*w)*16 + srow) * 768 + (ktv) + (kh)*32 + ssub], \
               &lds[32768 + (bufn)*18432 + (kh)*9216 + (2*w)*512]); \
    async_cp16(&Bt[(size_t)(nbase + (2*w+1)*16 + srow) * 768 + (ktv) + (kh)*32 + ssub], \
               &lds[32768 + (bufn)*18432 + (kh)*9216 + (2*w+1)*512]); \
    if (w < 2) { \
        async_cp16(&Bt[(size_t)(nbase + (16+w)*16 + srow) * 768 + (ktv) + (kh)*32 + ssub], \
                   &lds[32768 + (bufn)*18432 + (kh)*9216 + (16+w)*512]); } }

// 18 MFMA: m-pair (I0,I0+1) x 9 n-frags x one k-half. Per-fragment operand
// order: V-fragments (col>=1536) unswapped (lane=feature-major, R10-verified),
// Q/K swapped (lane=token-major, R8-verified).
#define PAIR(I0, kh, bufc) { \
    const b16x8 a0 = LDSA(bufc, kh, I0), a1 = LDSA(bufc, kh, (I0) + 1); \
    _Pragma("unroll") \
    for (int j = 0; j < 9; j++) { \
        if (colbase + j * 16 >= 1536) { \
            acc[I0][j]     = __builtin_amdgcn_mfma_f32_16x16x32_bf16(a0, bf[j], acc[I0][j], 0, 0, 0); \
            acc[(I0)+1][j] = __builtin_amdgcn_mfma_f32_16x16x32_bf16(a1, bf[j], acc[(I0)+1][j], 0, 0, 0); \
        } else { \
            acc[I0][j]     = __builtin_amdgcn_mfma_f32_16x16x32_bf16(bf[j], a0, acc[I0][j], 0, 0, 0); \
            acc[(I0)+1][j] = __builtin_amdgcn_mfma_f32_16x16x32_bf16(bf[j], a1, acc[(I0)+1][j], 0, 0, 0); \
        } } }

__global__ __launch_bounds__(512, 2)
void k_qkv(const ushort* __restrict__ A, const ushort* __restrict__ Bt,
           ushort* __restrict__ qo, ushort* __restrict__ ko,
           ushort* __restrict__ vo) {
    extern __shared__ ushort lds[];
    const int id   = blockIdx.x;          // 256 blocks; id%8 = XCD round-robin
    const int bx   = id & 7;              // one B-panel per XCD (0.44MB, L2-hit)
    const int by   = id >> 3;
    const int tid  = threadIdx.x;
    const int w    = tid >> 6;            // 8 waves
    const int lane = tid & 63;
    const int wm   = w >> 1, wn = w & 1;  // 4M x 2N -> per-wave 64x144
    const int m16  = lane & 15, q8 = (lane >> 4) * 8;
    const int mbase = by * 256, nbase = bx * 288;
    const int colbase = nbase + wn * 144;
    const int srow = lane >> 2, ssub = (lane & 3) * 8;

    f32x4 acc[4][9];
    #pragma unroll
    for (int i = 0; i < 4; i++)
        #pragma unroll
        for (int j = 0; j < 9; j++) acc[i][j] = (f32x4){0.f, 0.f, 0.f, 0.f};

    // prologue: K-step 0, both k-halves -> buf 0; land k0, keep k1 flying
    STA(0, 0, 0); STB(0, 0, 0);
    STA(0, 0, 1); STB(0, 0, 1);
    if (w < 2) { WAITV(5); } else { WAITV(4); }
    SBAR();

    b16x8 bf[9];
    int cur = 0;
    for (int t = 0; t < 12; t++) {
        const int kt  = t * 64;
        const int nxt = cur ^ 1;
        const bool more = (t < 11);
        // P0: read B(k0)+A(k0,i01); stage A(t+1,k0); MFMA
        #pragma unroll
        for (int j = 0; j < 9; j++) bf[j] = LDSB(cur, 0, j);
        if (more) STA(nxt, kt + 64, 0);
        __builtin_amdgcn_s_setprio(1);
        PAIR(0, 0, cur);
        __builtin_amdgcn_s_setprio(0);
        SBAR();
        // P1: A(k0,i23); stage B(t+1,k0); MFMA; then land cur-k1
        if (more) STB(nxt, kt + 64, 0);
        __builtin_amdgcn_s_setprio(1);
        PAIR(2, 0, cur);
        __builtin_amdgcn_s_setprio(0);
        if (more) { if (w < 2) { WAITV(5); } else { WAITV(4); } }
        else      { WAITV(0); }
        SBAR();
        // P2: read B(k1)+A(k1,i01); stage A(t+1,k1); MFMA
        #pragma unroll
        for (int j = 0; j < 9; j++) bf[j] = LDSB(cur, 1, j);
        if (more) STA(nxt, kt + 64, 1);
        __builtin_amdgcn_s_setprio(1);
        PAIR(0, 1, cur);
        __builtin_amdgcn_s_setprio(0);
        SBAR();
        // P3: A(k1,i23); stage B(t+1,k1); MFMA; land (t+1)-k0
        if (more) STB(nxt, kt + 64, 1);
        __builtin_amdgcn_s_setprio(1);
        PAIR(2, 1, cur);
        __builtin_amdgcn_s_setprio(0);
        if (more) {
            if (w < 2) { WAITV(5); } else { WAITV(4); }
            SBAR();
        }
        cur = nxt;
    }

    // epilogue: per 16-col fragment, Q/K (token-major acc) or V (feature-major)
    #pragma unroll
    for (int j = 0; j < 9; j++) {
        const int col16 = colbase + j * 16;
        if (col16 < 1536) {
            const int f0  = col16 + (q8 >> 1);      // + quad*4
            const int sp  = (f0 >= 768) ? 1 : 0;
            const int rem = f0 - sp * 768;
            const int h   = rem >> 6, d0 = rem & 63;
            ushort* base  = sp ? ko : qo;
            #pragma unroll
            for (int i = 0; i < 4; i++) {
                const int tok = mbase + wm * 64 + i * 16 + m16;
                const int b = tok >> 10, n = tok & 1023;
                ushort4 pk;
                pk.x = f2b(acc[i][j][0]); pk.y = f2b(acc[i][j][1]);
                pk.z = f2b(acc[i][j][2]); pk.w = f2b(acc[i][j][3]);
                *reinterpret_cast<ushort4*>(
                    &base[((size_t)(b * 12 + h) * 1024 + n) * 64 + d0]) = pk;
            }
        } else {
            const int f   = col16 + m16;
            const int rem = f - 1536;
            const int h   = rem >> 6, d0 = rem & 63;
            #pragma unroll
            for (int i = 0; i < 4; i++) {
                const int tok0 = mbase + wm * 64 + i * 16 + (q8 >> 1);
                const int b = tok0 >> 10, n0 = tok0 & 1023;
                ushort4 pk;
                pk.x = f2b(acc[i][j][0]); pk.y = f2b(acc[i][j][1]);
                pk.z = f2b(acc[i][j][2]); pk.w = f2b(acc[i][j][3]);
                *reinterpret_cast<ushort4*>(
                    &vo[((size_t)(b * 12 + h) * 64 + d0) * 1024 + n0]) = pk;
            }
        }
    }
}

// ---------------- k_proj: R8-baseline 128x128, BK=32, dbuf, f32+bias out ----------

__global__ __launch_bounds__(256, 2)
void k_proj(const ushort* __restrict__ A, const ushort* __restrict__ Bt,
            float* __restrict__ co, const float* __restrict__ bias,
            int N, int K) {
    __shared__ ushort As[2][128 * 32];
    __shared__ ushort Bs[2][128 * 32];
    const int id   = blockIdx.x;
    const int xcd  = id & 7;
    const int s    = id >> 3;
    const int by   = xcd * 8 + (s & 7);
    const int bx   = s >> 3;
    const int tid  = threadIdx.x;
    const int lane = tid & 63;
    const int w    = tid >> 6;
    const int wm   = w >> 1, wn = w & 1;
    const int m16  = lane & 15, quad = lane >> 4;
    const int mbase = by * 128, nbase = bx * 128;

    f32x4 acc[4][4];
    #pragma unroll
    for (int i = 0; i < 4; i++)
        #pragma unroll
        for (int j = 0; j < 4; j++) acc[i][j] = (f32x4){0.f, 0.f, 0.f, 0.f};

    const int rS = w * 32 + (lane >> 2);
    const int cS = (lane & 3) * 8;
    const int wOff0 = (w * 2 + 0) * 512;
    const int wOff1 = (w * 2 + 1) * 512;
    const ushort* gA0 = &A [(size_t)(mbase + rS)      * K + cS];
    const ushort* gA1 = &A [(size_t)(mbase + rS + 16) * K + cS];
    const ushort* gB0 = &Bt[(size_t)(nbase + rS)      * K + cS];
    const ushort* gB1 = &Bt[(size_t)(nbase + rS + 16) * K + cS];

    async_cp16(gA0, &As[0][wOff0]);
    async_cp16(gA1, &As[0][wOff1]);
    async_cp16(gB0, &Bs[0][wOff0]);
    async_cp16(gB1, &Bs[0][wOff1]);

    for (int kt = 0; kt < K; kt += 32) {
        const int cur = (kt >> 5) & 1, nxt = cur ^ 1;
        __syncthreads();
        if (kt + 32 < K) {
            async_cp16(gA0 + kt + 32, &As[nxt][wOff0]);
            async_cp16(gA1 + kt + 32, &As[nxt][wOff1]);
            async_cp16(gB0 + kt + 32, &Bs[nxt][wOff0]);
            async_cp16(gB1 + kt + 32, &Bs[nxt][wOff1]);
        }
        b16x8 af[4], bfr[4];
        #pragma unroll
        for (int i = 0; i < 4; i++)
            af[i] = *reinterpret_cast<const b16x8*>(&As[cur][(wm * 64 + i * 16 + m16) * 32 + quad * 8]);
        #pragma unroll
        for (int j = 0; j < 4; j++)
            bfr[j] = *reinterpret_cast<const b16x8*>(&Bs[cur][(wn * 64 + j * 16 + m16) * 32 + quad * 8]);
        #pragma unroll
        for (int i = 0; i < 4; i++)
            #pragma unroll
            for (int j = 0; j < 4; j++)
                acc[i][j] = __builtin_amdgcn_mfma_f32_16x16x32_bf16(bfr[j], af[i], acc[i][j], 0, 0, 0);
    }

    #pragma unroll
    for (int j = 0; j < 4; j++) {
        const int f0 = nbase + wn * 64 + j * 16 + quad * 4;
        #pragma unroll
        for (int i = 0; i < 4; i++) {
            const int tok = mbase + wm * 64 + i * 16 + m16;
            float4 val;
            val.x = acc[i][j][0] + bias[f0 + 0];
            val.y = acc[i][j][1] + bias[f0 + 1];
            val.z = acc[i][j][2] + bias[f0 + 2];
            val.w = acc[i][j][3] + bias[f0 + 3];
            *reinterpret_cast<float4*>(&co[(size_t)tok * N + f0]) = val;
        }
    }
}

// ---------------- attention: flash, LDS-staged K/V, Q-blocked x2 (unchanged) ----------

#define AP 72   // LDS row pitch (elements)

__global__ __launch_bounds__(256)
void k_attn(const ushort* __restrict__ qa, const ushort* __restrict__ ka,
            const ushort* __restrict__ vt, ushort* __restrict__ ao) {
    __shared__ ushort Ks[64 * AP];
    __shared__ ushort Vs[64 * AP];

    const int l    = blockIdx.x;               // 0..767
    const int xcd  = l & 7;
    const int g    = l >> 3;                   // 0..95
    const int head = (g % 12) * 8 + xcd;       // head%8 == xcd -> XCD locality
    const int qsup = g / 12;                   // 0..7 (128-row supertile)
    const int tid  = threadIdx.x;
    const int w    = tid >> 6;
    const int lane = tid & 63;
    const int n    = lane & 15;
    const int q    = lane >> 4;

    const ushort* qh = qa + (size_t)head * 65536;
    const ushort* kh = ka + (size_t)head * 65536;
    const ushort* vh = vt + (size_t)head * 65536;
    const int qrow0 = qsup * 128 + w * 32;

    b16x8 bq0[2], bq1[2];
    #pragma unroll
    for (int u = 0; u < 2; u++) {
        bq0[u] = *reinterpret_cast<const b16x8*>(&qh[(qrow0 + u * 16 + n) * 64 + q * 8]);
        bq1[u] = *reinterpret_cast<const b16x8*>(&qh[(qrow0 + u * 16 + n) * 64 + 32 + q * 8]);
    }

    const int kr0 = tid >> 3, kc0 = (tid & 7) * 8;
    const int kr1 = kr0 + 32, kc1 = kc0;

    int4 kg0, kg1, vg0, vg1;
    kg0 = *reinterpret_cast<const int4*>(&kh[(0 + kr0) * 64 + kc0]);
    kg1 = *reinterpret_cast<const int4*>(&kh[(0 + kr1) * 64 + kc1]);
    vg0 = *reinterpret_cast<const int4*>(&vh[kr0 * 1024 + 0 + kc0]);
    vg1 = *reinterpret_cast<const int4*>(&vh[kr1 * 1024 + 0 + kc1]);

    f32x4 o[2][4];
    #pragma unroll
    for (int u = 0; u < 2; u++)
        #pragma unroll
        for (int dt = 0; dt < 4; dt++) o[u][dt] = (f32x4){0, 0, 0, 0};
    float Lacc[2] = {0.f, 0.f};

    const float SC = 0.125f * 1.4426950408889634f;
    const int s0 = ((q & 1) * 2) * 16 + n;
    const int s1 = s0 + 16;
    const bool lowq = (q < 2);

    for (int m0 = 0; m0 < 1024; m0 += 64) {
        *reinterpret_cast<int4*>(&Ks[kr0 * AP + kc0]) = kg0;
        *reinterpret_cast<int4*>(&Ks[kr1 * AP + kc1]) = kg1;
        *reinterpret_cast<int4*>(&Vs[kr0 * AP + kc0]) = vg0;
        *reinterpret_cast<int4*>(&Vs[kr1 * AP + kc1]) = vg1;
        __syncthreads();

        if (m0 + 64 < 1024) {
            kg0 = *reinterpret_cast<const int4*>(&kh[(m0 + 64 + kr0) * 64 + kc0]);
            kg1 = *reinterpret_cast<const int4*>(&kh[(m0 + 64 + kr1) * 64 + kc1]);
            vg0 = *reinterpret_cast<const int4*>(&vh[kr0 * 1024 + m0 + 64 + kc0]);
            vg1 = *reinterpret_cast<const int4*>(&vh[kr1 * 1024 + m0 + 64 + kc1]);
        }

        #pragma unroll
        for (int mc = 0; mc < 2; mc++) {
            b16x8 ka0t[2], ka1t[2];
            #pragma unroll
            for (int t = 0; t < 2; t++) {
                ka0t[t] = *reinterpret_cast<const b16x8*>(&Ks[(mc * 32 + t * 16 + n) * AP + q * 8]);
                ka1t[t] = *reinterpret_cast<const b16x8*>(&Ks[(mc * 32 + t * 16 + n) * AP + 32 + q * 8]);
            }
            f32x4 st[2][2];
            #pragma unroll
            for (int u = 0; u < 2; u++)
                #pragma unroll
                for (int t = 0; t < 2; t++) {
                    st[u][t] = (f32x4){0, 0, 0, 0};
                    st[u][t] = __builtin_amdgcn_mfma_f32_16x16x32_bf16(ka0t[t], bq0[u], st[u][t], 0, 0, 0);
                    st[u][t] = __builtin_amdgcn_mfma_f32_16x16x32_bf16(ka1t[t], bq1[u], st[u][t], 0, 0, 0);
                }

            union { uint4 u4; b16x8 v; } bp[2];
            #pragma unroll
            for (int u = 0; u < 2; u++) {
                float p00 = __builtin_amdgcn_exp2f(st[u][0][0] * SC);
                float p01 = __builtin_amdgcn_exp2f(st[u][0][1] * SC);
                float p02 = __builtin_amdgcn_exp2f(st[u][0][2] * SC);
                float p03 = __builtin_amdgcn_exp2f(st[u][0][3] * SC);
                float p10 = __builtin_amdgcn_exp2f(st[u][1][0] * SC);
                float p11 = __builtin_amdgcn_exp2f(st[u][1][1] * SC);
                float p12 = __builtin_amdgcn_exp2f(st[u][1][2] * SC);
                float p13 = __builtin_amdgcn_exp2f(st[u][1][3] * SC);
                Lacc[u] += ((p00 + p01) + (p02 + p03)) + ((p10 + p11) + (p12 + p13));

                const uint pk00 = packbf(p00, p01), pk01 = packbf(p02, p03);
                const uint pk10 = packbf(p10, p11), pk11 = packbf(p12, p13);

                uint a, b, dw0, dw1, dw2, dw3;
                a = __shfl((int)pk00, s0); b = __shfl((int)pk10, s0); dw0 = lowq ? a : b;
                a = __shfl((int)pk01, s0); b = __shfl((int)pk11, s0); dw1 = lowq ? a : b;
                a = __shfl((int)pk00, s1); b = __shfl((int)pk10, s1); dw2 = lowq ? a : b;
                a = __shfl((int)pk01, s1); b = __shfl((int)pk11, s1); dw3 = lowq ? a : b;
                bp[u].u4 = (uint4){dw0, dw1, dw2, dw3};
            }

            #pragma unroll
            for (int dt = 0; dt < 4; dt++) {
                const b16x8 av = *reinterpret_cast<const b16x8*>(
                    &Vs[(dt * 16 + n) * AP + mc * 32 + q * 8]);
                #pragma unroll
                for (int u = 0; u < 2; u++)
                    o[u][dt] = __builtin_amdgcn_mfma_f32_16x16x32_bf16(av, bp[u].v, o[u][dt], 0, 0, 0);
            }
        }
        __syncthreads();
    }

    const int bb = head / 12, h = head - bb * 12;
    #pragma unroll
    for (int u = 0; u < 2; u++) {
        float L = Lacc[u];
        L += __shfl_xor(L, 16);
        L += __shfl_xor(L, 32);
        const float inv = 1.f / L;
        ushort* dst = ao + ((size_t)(bb * 1024 + qrow0 + u * 16 + n)) * 768 + h * 64 + q * 4;
        #pragma unroll
        for (int dt = 0; dt < 4; dt++) {
            ushort4 pk;
            pk.x = f2b(o[u][dt][0] * inv);
            pk.y = f2b(o[u][dt][1] * inv);
            pk.z = f2b(o[u][dt][2] * inv);
            pk.w = f2b(o[u][dt][3] * inv);
            *reinterpret_cast<ushort4*>(dst + dt * 16) = pk;
        }
    }
}

// ---------------- launch ----------------

extern "C" void kernel_launch(void* const* d_in, const int* in_sizes, int n_in,
                              void* d_out, int out_size, void* d_ws, size_t ws_size,
                              hipStream_t stream) {
    (void)in_sizes; (void)n_in; (void)out_size; (void)ws_size;
    const float* x     = (const float*)d_in[0];
    const float* Wqkv  = (const float*)d_in[4];
    const float* Wproj = (const float*)d_in[5];
    const float* bproj = (const float*)d_in[6];
    float* out = (float*)d_out;

    char* ws = (char*)d_ws;
    ushort* xb     = (ushort*)ws; ws += (size_t)8192 * 768 * 2;
    ushort* wqkvt  = (ushort*)ws; ws += (size_t)2304 * 768 * 2;
    ushort* wprojt = (ushort*)ws; ws += (size_t)768  * 768 * 2;
    ushort* qa     = (ushort*)ws; ws += (size_t)96 * 1024 * 64 * 2;
    ushort* ka     = (ushort*)ws; ws += (size_t)96 * 1024 * 64 * 2;
    ushort* vt     = (ushort*)ws; ws += (size_t)96 * 64 * 1024 * 2;
    ushort* ao     = (ushort*)ws; ws += (size_t)8192 * 768 * 2;

    static int attr_set = 0;
    if (!attr_set) {
        hipFuncSetAttribute((const void*)k_qkv,
                            hipFuncAttributeMaxDynamicSharedMemorySize, 139264);
        attr_set = 1;
    }

    k_prep<<<dim3(6720), dim3(256), 0, stream>>>(x, xb, Wqkv, wqkvt, Wproj, wprojt);
    k_qkv<<<dim3(256), dim3(512), 139264, stream>>>(xb, wqkvt, qa, ka, vt);
    k_attn<<<dim3(768), dim3(256), 0, stream>>>(qa, ka, vt, ao);
    k_proj<<<dim3(384), dim3(256), 0, stream>>>(ao, wprojt, out, bproj, 768, 768);
}

// Round 4
// 367.082 us; speedup vs baseline: 1.0521x; 1.0521x over previous
//
#include <hip/hip_runtime.h>
#include <hip/hip_bf16.h>

// LogoAwareAttention: B=8, N=1024, C=768, H=12, Dh=64.
// Per-(b,h) scalar logit bias cancels in softmax -> dropped.
//
// R12 (evidence: R11's 8-phase k_qkv had VGPR_Count==128 exactly =
// 512/4 -> __launch_bounds__(512,2) acted as min-BLOCKS/CU (CUDA
// semantics): 2 blocks x 8 waves = 4 waves/SIMD -> 128-reg cap < 144-reg
// accumulator -> catastrophic scratch spill (FETCH 340MB / WRITE 445MB,
// MfmaUtil 5%). The pipeline itself passed correctness. Fix the budget,
// keep the schedule):
//  1. launch_bounds(512) + amdgpu_waves_per_eu(2): 256-reg budget,
//     1 block/CU (LDS 136KB forces this anyway). Demand ~228 -> no spill.
//  2. Hoisted per-thread global base pointers (less addr pressure).
//  3. T2 st_16x32 swizzle, now regime-legal (8-phase): pre-swizzled
//     GLOBAL source col (ssub^=(srow&8)?16:0) + same XOR on ds_read col
//     (q8s) -- both-sides involution per rule 21; linear LDS dest kept
//     (global_load_lds requirement). Kills stride-64B 8-way conflicts.

typedef __bf16 b16x8 __attribute__((ext_vector_type(8)));
typedef float f32x4 __attribute__((ext_vector_type(4)));

__device__ __forceinline__ ushort f2b(float f) {
    union { float f; uint u; } v; v.f = f;
    uint u = v.u;
    u += 0x7fffu + ((u >> 16) & 1u);   // round-to-nearest-even
    return (ushort)(u >> 16);
}

__device__ __forceinline__ uint packbf(float a, float b) {
    union { float f; uint u; } ua, ub; ua.f = a; ub.f = b;
    return ((ua.u + 0x8000u) >> 16) | ((ub.u + 0x8000u) & 0xffff0000u);
}

// async 16B-per-lane global->LDS copy; lds dest = wave-uniform base + lane*16
__device__ __forceinline__ void async_cp16(const void* g, void* l) {
    __builtin_amdgcn_global_load_lds(
        (const __attribute__((address_space(1))) unsigned int*)g,
        (__attribute__((address_space(3))) unsigned int*)l, 16, 0, 0);
}

// ---------------- fused prep: x->bf16 | Wqkv^T | Wproj^T ----------------
// blocks [0,6144): conv;  [6144,6576): Wqkv transpose;  [6576,6720): Wproj.

__global__ __launch_bounds__(256)
void k_prep(const float* __restrict__ x, ushort* __restrict__ xb,
            const float* __restrict__ Wqkv, ushort* __restrict__ wqkvt,
            const float* __restrict__ Wproj, ushort* __restrict__ wprojt) {
    __shared__ ushort T[64][65];
    const int blk = blockIdx.x;
    const int t   = threadIdx.x;

    if (blk < 6144) {
        const int i = blk * 256 + t;
        const float4 v = reinterpret_cast<const float4*>(x)[i];
        ushort4 o;
        o.x = f2b(v.x); o.y = f2b(v.y); o.z = f2b(v.z); o.w = f2b(v.w);
        reinterpret_cast<ushort4*>(xb)[i] = o;
        return;
    }

    const bool isqkv = (blk < 6576);
    const int idx = isqkv ? (blk - 6144) : (blk - 6576);
    const int Nin = isqkv ? 2304 : 768;
    const float* W  = isqkv ? Wqkv : Wproj;
    ushort* Wt      = isqkv ? wqkvt : wprojt;
    const int k0 = (idx % 12) * 64;
    const int n0 = (idx / 12) * 64;
    const int r  = t >> 4, cg = (t & 15) * 4;
    #pragma unroll
    for (int rr = 0; rr < 64; rr += 16) {
        const float4 v = *reinterpret_cast<const float4*>(&W[(size_t)(k0 + r + rr) * Nin + n0 + cg]);
        T[r + rr][cg + 0] = f2b(v.x); T[r + rr][cg + 1] = f2b(v.y);
        T[r + rr][cg + 2] = f2b(v.z); T[r + rr][cg + 3] = f2b(v.w);
    }
    __syncthreads();
    #pragma unroll
    for (int rr = 0; rr < 64; rr += 16) {
        ushort4 o;
        o.x = T[cg + 0][r + rr]; o.y = T[cg + 1][r + rr];
        o.z = T[cg + 2][r + rr]; o.w = T[cg + 3][r + rr];
        *reinterpret_cast<ushort4*>(&Wt[(size_t)(n0 + r + rr) * 768 + k0 + cg]) = o;
    }
}

// ---------------- k_qkv: 256x288 tile, BK=64, 8 waves, 4-phase pipeline ----------

#define SBAR()   asm volatile("s_barrier" ::: "memory")
#define WAITV(n) asm volatile("s_waitcnt vmcnt(" #n ")" ::: "memory")

// LDS element offsets (ushort): A[buf] at buf*16384 (2x 256x64), B[buf] at
// 32768 + buf*18432 (2x 288x64); per k-half sections of [rows][32].
// q8s = swizzled read col (pairs with the pre-swizzled global source col).
#define LDSA(buf, kh, ii) (*reinterpret_cast<const b16x8*>( \
    &lds[(buf) * 16384 + (kh) * 8192 + (wm * 64 + (ii) * 16 + m16) * 32 + q8s]))
#define LDSB(buf, kh, jj) (*reinterpret_cast<const b16x8*>( \
    &lds[32768 + (buf) * 18432 + (kh) * 9216 + (wn * 144 + (jj) * 16 + m16) * 32 + q8s]))

// stage one k-half of A (2 loads/thread) / B (2, +1 for waves 0-1)
#define STA(bufn, ktv, kh) { \
    async_cp16(aA0 + (ktv) + (kh) * 32, &lds[(bufn)*16384 + (kh)*8192 + (2*w)*512]); \
    async_cp16(aA1 + (ktv) + (kh) * 32, &lds[(bufn)*16384 + (kh)*8192 + (2*w+1)*512]); }
#define STB(bufn, ktv, kh) { \
    async_cp16(aB0 + (ktv) + (kh) * 32, &lds[32768 + (bufn)*18432 + (kh)*9216 + (2*w)*512]); \
    async_cp16(aB1 + (ktv) + (kh) * 32, &lds[32768 + (bufn)*18432 + (kh)*9216 + (2*w+1)*512]); \
    if (w < 2) { \
        async_cp16(aB2 + (ktv) + (kh) * 32, &lds[32768 + (bufn)*18432 + (kh)*9216 + (16+w)*512]); } }

// 18 MFMA: m-pair (I0,I0+1) x 9 n-frags x one k-half. Per-fragment operand
// order: V-fragments (col>=1536) unswapped (lane=feature-major), Q/K swapped
// (lane=token-major). Both layouts refcheck-verified (R8/R10/R11 passes).
#define PAIR(I0, kh, bufc) { \
    const b16x8 a0 = LDSA(bufc, kh, I0), a1 = LDSA(bufc, kh, (I0) + 1); \
    _Pragma("unroll") \
    for (int j = 0; j < 9; j++) { \
        if (colbase + j * 16 >= 1536) { \
            acc[I0][j]     = __builtin_amdgcn_mfma_f32_16x16x32_bf16(a0, bf[j], acc[I0][j], 0, 0, 0); \
            acc[(I0)+1][j] = __builtin_amdgcn_mfma_f32_16x16x32_bf16(a1, bf[j], acc[(I0)+1][j], 0, 0, 0); \
        } else { \
            acc[I0][j]     = __builtin_amdgcn_mfma_f32_16x16x32_bf16(bf[j], a0, acc[I0][j], 0, 0, 0); \
            acc[(I0)+1][j] = __builtin_amdgcn_mfma_f32_16x16x32_bf16(bf[j], a1, acc[(I0)+1][j], 0, 0, 0); \
        } } }

__global__ __launch_bounds__(512) __attribute__((amdgpu_waves_per_eu(2)))
void k_qkv(const ushort* __restrict__ A, const ushort* __restrict__ Bt,
           ushort* __restrict__ qo, ushort* __restrict__ ko,
           ushort* __restrict__ vo) {
    extern __shared__ ushort lds[];
    const int id   = blockIdx.x;          // 256 blocks; id%8 = XCD round-robin
    const int bx   = id & 7;              // one B-panel per XCD (0.44MB, L2-hit)
    const int by   = id >> 3;
    const int tid  = threadIdx.x;
    const int w    = tid >> 6;            // 8 waves
    const int lane = tid & 63;
    const int wm   = w >> 1, wn = w & 1;  // 4M x 2N -> per-wave 64x144
    const int m16  = lane & 15, q8 = (lane >> 4) * 8;
    const int q8s  = q8 ^ ((m16 & 8) ? 16 : 0);     // T2 read-side XOR
    const int mbase = by * 256, nbase = bx * 288;
    const int colbase = nbase + wn * 144;
    const int srow = lane >> 2;
    const int ssub = ((lane & 3) * 8) ^ ((srow & 8) ? 16 : 0);  // T2 source XOR

    // per-thread staging base pointers (hoisted; loop adds small const offs)
    const ushort* aA0 = &A [(size_t)(mbase + (2 * w)     * 16 + srow) * 768 + ssub];
    const ushort* aA1 = &A [(size_t)(mbase + (2 * w + 1) * 16 + srow) * 768 + ssub];
    const ushort* aB0 = &Bt[(size_t)(nbase + (2 * w)     * 16 + srow) * 768 + ssub];
    const ushort* aB1 = &Bt[(size_t)(nbase + (2 * w + 1) * 16 + srow) * 768 + ssub];
    const ushort* aB2 = &Bt[(size_t)(nbase + (16 + (w & 1)) * 16 + srow) * 768 + ssub];

    f32x4 acc[4][9];
    #pragma unroll
    for (int i = 0; i < 4; i++)
        #pragma unroll
        for (int j = 0; j < 9; j++) acc[i][j] = (f32x4){0.f, 0.f, 0.f, 0.f};

    // prologue: K-step 0, both k-halves -> buf 0; land k0, keep k1 flying
    STA(0, 0, 0); STB(0, 0, 0);
    STA(0, 0, 1); STB(0, 0, 1);
    if (w < 2) { WAITV(5); } else { WAITV(4); }
    SBAR();

    b16x8 bf[9];
    int cur = 0;
    for (int t = 0; t < 12; t++) {
        const int kt  = t * 64;
        const int nxt = cur ^ 1;
        const bool more = (t < 11);
        // P0: read B(k0)+A(k0,i01); stage A(t+1,k0); MFMA
        #pragma unroll
        for (int j = 0; j < 9; j++) bf[j] = LDSB(cur, 0, j);
        if (more) STA(nxt, kt + 64, 0);
        __builtin_amdgcn_s_setprio(1);
        PAIR(0, 0, cur);
        __builtin_amdgcn_s_setprio(0);
        SBAR();
        // P1: A(k0,i23); stage B(t+1,k0); MFMA; then land cur-k1
        if (more) STB(nxt, kt + 64, 0);
        __builtin_amdgcn_s_setprio(1);
        PAIR(2, 0, cur);
        __builtin_amdgcn_s_setprio(0);
        if (more) { if (w < 2) { WAITV(5); } else { WAITV(4); } }
        else      { WAITV(0); }
        SBAR();
        // P2: read B(k1)+A(k1,i01); stage A(t+1,k1); MFMA
        #pragma unroll
        for (int j = 0; j < 9; j++) bf[j] = LDSB(cur, 1, j);
        if (more) STA(nxt, kt + 64, 1);
        __builtin_amdgcn_s_setprio(1);
        PAIR(0, 1, cur);
        __builtin_amdgcn_s_setprio(0);
        SBAR();
        // P3: A(k1,i23); stage B(t+1,k1); MFMA; land (t+1)-k0
        if (more) STB(nxt, kt + 64, 1);
        __builtin_amdgcn_s_setprio(1);
        PAIR(2, 1, cur);
        __builtin_amdgcn_s_setprio(0);
        if (more) {
            if (w < 2) { WAITV(5); } else { WAITV(4); }
            SBAR();
        }
        cur = nxt;
    }

    // epilogue: per 16-col fragment, Q/K (token-major acc) or V (feature-major)
    #pragma unroll
    for (int j = 0; j < 9; j++) {
        const int col16 = colbase + j * 16;
        if (col16 < 1536) {
            const int f0  = col16 + (q8 >> 1);      // + quad*4
            const int sp  = (f0 >= 768) ? 1 : 0;
            const int rem = f0 - sp * 768;
            const int h   = rem >> 6, d0 = rem & 63;
            ushort* base  = sp ? ko : qo;
            #pragma unroll
            for (int i = 0; i < 4; i++) {
                const int tok = mbase + wm * 64 + i * 16 + m16;
                const int b = tok >> 10, n = tok & 1023;
                ushort4 pk;
                pk.x = f2b(acc[i][j][0]); pk.y = f2b(acc[i][j][1]);
                pk.z = f2b(acc[i][j][2]); pk.w = f2b(acc[i][j][3]);
                *reinterpret_cast<ushort4*>(
                    &base[((size_t)(b * 12 + h) * 1024 + n) * 64 + d0]) = pk;
            }
        } else {
            const int f   = col16 + m16;
            const int rem = f - 1536;
            const int h   = rem >> 6, d0 = rem & 63;
            #pragma unroll
            for (int i = 0; i < 4; i++) {
                const int tok0 = mbase + wm * 64 + i * 16 + (q8 >> 1);
                const int b = tok0 >> 10, n0 = tok0 & 1023;
                ushort4 pk;
                pk.x = f2b(acc[i][j][0]); pk.y = f2b(acc[i][j][1]);
                pk.z = f2b(acc[i][j][2]); pk.w = f2b(acc[i][j][3]);
                *reinterpret_cast<ushort4*>(
                    &vo[((size_t)(b * 12 + h) * 64 + d0) * 1024 + n0]) = pk;
            }
        }
    }
}

// ---------------- k_proj: R8-baseline 128x128, BK=32, dbuf, f32+bias out ----------

__global__ __launch_bounds__(256, 2)
void k_proj(const ushort* __restrict__ A, const ushort* __restrict__ Bt,
            float* __restrict__ co, const float* __restrict__ bias,
            int N, int K) {
    __shared__ ushort As[2][128 * 32];
    __shared__ ushort Bs[2][128 * 32];
    const int id   = blockIdx.x;
    const int xcd  = id & 7;
    const int s    = id >> 3;
    const int by   = xcd * 8 + (s & 7);
    const int bx   = s >> 3;
    const int tid  = threadIdx.x;
    const int lane = tid & 63;
    const int w    = tid >> 6;
    const int wm   = w >> 1, wn = w & 1;
    const int m16  = lane & 15, quad = lane >> 4;
    const int mbase = by * 128, nbase = bx * 128;

    f32x4 acc[4][4];
    #pragma unroll
    for (int i = 0; i < 4; i++)
        #pragma unroll
        for (int j = 0; j < 4; j++) acc[i][j] = (f32x4){0.f, 0.f, 0.f, 0.f};

    const int rS = w * 32 + (lane >> 2);
    const int cS = (lane & 3) * 8;
    const int wOff0 = (w * 2 + 0) * 512;
    const int wOff1 = (w * 2 + 1) * 512;
    const ushort* gA0 = &A [(size_t)(mbase + rS)      * K + cS];
    const ushort* gA1 = &A [(size_t)(mbase + rS + 16) * K + cS];
    const ushort* gB0 = &Bt[(size_t)(nbase + rS)      * K + cS];
    const ushort* gB1 = &Bt[(size_t)(nbase + rS + 16) * K + cS];

    async_cp16(gA0, &As[0][wOff0]);
    async_cp16(gA1, &As[0][wOff1]);
    async_cp16(gB0, &Bs[0][wOff0]);
    async_cp16(gB1, &Bs[0][wOff1]);

    for (int kt = 0; kt < K; kt += 32) {
        const int cur = (kt >> 5) & 1, nxt = cur ^ 1;
        __syncthreads();
        if (kt + 32 < K) {
            async_cp16(gA0 + kt + 32, &As[nxt][wOff0]);
            async_cp16(gA1 + kt + 32, &As[nxt][wOff1]);
            async_cp16(gB0 + kt + 32, &Bs[nxt][wOff0]);
            async_cp16(gB1 + kt + 32, &Bs[nxt][wOff1]);
        }
        b16x8 af[4], bfr[4];
        #pragma unroll
        for (int i = 0; i < 4; i++)
            af[i] = *reinterpret_cast<const b16x8*>(&As[cur][(wm * 64 + i * 16 + m16) * 32 + quad * 8]);
        #pragma unroll
        for (int j = 0; j < 4; j++)
            bfr[j] = *reinterpret_cast<const b16x8*>(&Bs[cur][(wn * 64 + j * 16 + m16) * 32 + quad * 8]);
        #pragma unroll
        for (int i = 0; i < 4; i++)
            #pragma unroll
            for (int j = 0; j < 4; j++)
                acc[i][j] = __builtin_amdgcn_mfma_f32_16x16x32_bf16(bfr[j], af[i], acc[i][j], 0, 0, 0);
    }

    #pragma unroll
    for (int j = 0; j < 4; j++) {
        const int f0 = nbase + wn * 64 + j * 16 + quad * 4;
        #pragma unroll
        for (int i = 0; i < 4; i++) {
            const int tok = mbase + wm * 64 + i * 16 + m16;
            float4 val;
            val.x = acc[i][j][0] + bias[f0 + 0];
            val.y = acc[i][j][1] + bias[f0 + 1];
            val.z = acc[i][j][2] + bias[f0 + 2];
            val.w = acc[i][j][3] + bias[f0 + 3];
            *reinterpret_cast<float4*>(&co[(size_t)tok * N + f0]) = val;
        }
    }
}

// ---------------- attention: flash, LDS-staged K/V, Q-blocked x2 (unchanged) ----------

#define AP 72   // LDS row pitch (elements)

__global__ __launch_bounds__(256)
void k_attn(const ushort* __restrict__ qa, const ushort* __restrict__ ka,
            const ushort* __restrict__ vt, ushort* __restrict__ ao) {
    __shared__ ushort Ks[64 * AP];
    __shared__ ushort Vs[64 * AP];

    const int l    = blockIdx.x;               // 0..767
    const int xcd  = l & 7;
    const int g    = l >> 3;                   // 0..95
    const int head = (g % 12) * 8 + xcd;       // head%8 == xcd -> XCD locality
    const int qsup = g / 12;                   // 0..7 (128-row supertile)
    const int tid  = threadIdx.x;
    const int w    = tid >> 6;
    const int lane = tid & 63;
    const int n    = lane & 15;
    const int q    = lane >> 4;

    const ushort* qh = qa + (size_t)head * 65536;
    const ushort* kh = ka + (size_t)head * 65536;
    const ushort* vh = vt + (size_t)head * 65536;
    const int qrow0 = qsup * 128 + w * 32;

    b16x8 bq0[2], bq1[2];
    #pragma unroll
    for (int u = 0; u < 2; u++) {
        bq0[u] = *reinterpret_cast<const b16x8*>(&qh[(qrow0 + u * 16 + n) * 64 + q * 8]);
        bq1[u] = *reinterpret_cast<const b16x8*>(&qh[(qrow0 + u * 16 + n) * 64 + 32 + q * 8]);
    }

    const int kr0 = tid >> 3, kc0 = (tid & 7) * 8;
    const int kr1 = kr0 + 32, kc1 = kc0;

    int4 kg0, kg1, vg0, vg1;
    kg0 = *reinterpret_cast<const int4*>(&kh[(0 + kr0) * 64 + kc0]);
    kg1 = *reinterpret_cast<const int4*>(&kh[(0 + kr1) * 64 + kc1]);
    vg0 = *reinterpret_cast<const int4*>(&vh[kr0 * 1024 + 0 + kc0]);
    vg1 = *reinterpret_cast<const int4*>(&vh[kr1 * 1024 + 0 + kc1]);

    f32x4 o[2][4];
    #pragma unroll
    for (int u = 0; u < 2; u++)
        #pragma unroll
        for (int dt = 0; dt < 4; dt++) o[u][dt] = (f32x4){0, 0, 0, 0};
    float Lacc[2] = {0.f, 0.f};

    const float SC = 0.125f * 1.4426950408889634f;
    const int s0 = ((q & 1) * 2) * 16 + n;
    const int s1 = s0 + 16;
    const bool lowq = (q < 2);

    for (int m0 = 0; m0 < 1024; m0 += 64) {
        *reinterpret_cast<int4*>(&Ks[kr0 * AP + kc0]) = kg0;
        *reinterpret_cast<int4*>(&Ks[kr1 * AP + kc1]) = kg1;
        *reinterpret_cast<int4*>(&Vs[kr0 * AP + kc0]) = vg0;
        *reinterpret_cast<int4*>(&Vs[kr1 * AP + kc1]) = vg1;
        __syncthreads();

        if (m0 + 64 < 1024) {
            kg0 = *reinterpret_cast<const int4*>(&kh[(m0 + 64 + kr0) * 64 + kc0]);
            kg1 = *reinterpret_cast<const int4*>(&kh[(m0 + 64 + kr1) * 64 + kc1]);
            vg0 = *reinterpret_cast<const int4*>(&vh[kr0 * 1024 + m0 + 64 + kc0]);
            vg1 = *reinterpret_cast<const int4*>(&vh[kr1 * 1024 + m0 + 64 + kc1]);
        }

        #pragma unroll
        for (int mc = 0; mc < 2; mc++) {
            b16x8 ka0t[2], ka1t[2];
            #pragma unroll
            for (int t = 0; t < 2; t++) {
                ka0t[t] = *reinterpret_cast<const b16x8*>(&Ks[(mc * 32 + t * 16 + n) * AP + q * 8]);
                ka1t[t] = *reinterpret_cast<const b16x8*>(&Ks[(mc * 32 + t * 16 + n) * AP + 32 + q * 8]);
            }
            f32x4 st[2][2];
            #pragma unroll
            for (int u = 0; u < 2; u++)
                #pragma unroll
                for (int t = 0; t < 2; t++) {
                    st[u][t] = (f32x4){0, 0, 0, 0};
                    st[u][t] = __builtin_amdgcn_mfma_f32_16x16x32_bf16(ka0t[t], bq0[u], st[u][t], 0, 0, 0);
                    st[u][t] = __builtin_amdgcn_mfma_f32_16x16x32_bf16(ka1t[t], bq1[u], st[u][t], 0, 0, 0);
                }

            union { uint4 u4; b16x8 v; } bp[2];
            #pragma unroll
            for (int u = 0; u < 2; u++) {
                float p00 = __builtin_amdgcn_exp2f(st[u][0][0] * SC);
                float p01 = __builtin_amdgcn_exp2f(st[u][0][1] * SC);
                float p02 = __builtin_amdgcn_exp2f(st[u][0][2] * SC);
                float p03 = __builtin_amdgcn_exp2f(st[u][0][3] * SC);
                float p10 = __builtin_amdgcn_exp2f(st[u][1][0] * SC);
                float p11 = __builtin_amdgcn_exp2f(st[u][1][1] * SC);
                float p12 = __builtin_amdgcn_exp2f(st[u][1][2] * SC);
                float p13 = __builtin_amdgcn_exp2f(st[u][1][3] * SC);
                Lacc[u] += ((p00 + p01) + (p02 + p03)) + ((p10 + p11) + (p12 + p13));

                const uint pk00 = packbf(p00, p01), pk01 = packbf(p02, p03);
                const uint pk10 = packbf(p10, p11), pk11 = packbf(p12, p13);

                uint a, b, dw0, dw1, dw2, dw3;
                a = __shfl((int)pk00, s0); b = __shfl((int)pk10, s0); dw0 = lowq ? a : b;
                a = __shfl((int)pk01, s0); b = __shfl((int)pk11, s0); dw1 = lowq ? a : b;
                a = __shfl((int)pk00, s1); b = __shfl((int)pk10, s1); dw2 = lowq ? a : b;
                a = __shfl((int)pk01, s1); b = __shfl((int)pk11, s1); dw3 = lowq ? a : b;
                bp[u].u4 = (uint4){dw0, dw1, dw2, dw3};
            }

            #pragma unroll
            for (int dt = 0; dt < 4; dt++) {
                const b16x8 av = *reinterpret_cast<const b16x8*>(
                    &Vs[(dt * 16 + n) * AP + mc * 32 + q * 8]);
                #pragma unroll
                for (int u = 0; u < 2; u++)
                    o[u][dt] = __builtin_amdgcn_mfma_f32_16x16x32_bf16(av, bp[u].v, o[u][dt], 0, 0, 0);
            }
        }
        __syncthreads();
    }

    const int bb = head / 12, h = head - bb * 12;
    #pragma unroll
    for (int u = 0; u < 2; u++) {
        float L = Lacc[u];
        L += __shfl_xor(L, 16);
        L += __shfl_xor(L, 32);
        const float inv = 1.f / L;
        ushort* dst = ao + ((size_t)(bb * 1024 + qrow0 + u * 16 + n)) * 768 + h * 64 + q * 4;
        #pragma unroll
        for (int dt = 0; dt < 4; dt++) {
            ushort4 pk;
            pk.x = f2b(o[u][dt][0] * inv);
            pk.y = f2b(o[u][dt][1] * inv);
            pk.z = f2b(o[u][dt][2] * inv);
            pk.w = f2b(o[u][dt][3] * inv);
            *reinterpret_cast<ushort4*>(dst + dt * 16) = pk;
        }
    }
}

// ---------------- launch ----------------

extern "C" void kernel_launch(void* const* d_in, const int* in_sizes, int n_in,
                              void* d_out, int out_size, void* d_ws, size_t ws_size,
                              hipStream_t stream) {
    (void)in_sizes; (void)n_in; (void)out_size; (void)ws_size;
    const float* x     = (const float*)d_in[0];
    const float* Wqkv  = (const float*)d_in[4];
    const float* Wproj = (const float*)d_in[5];
    const float* bproj = (const float*)d_in[6];
    float* out = (float*)d_out;

    char* ws = (char*)d_ws;
    ushort* xb     = (ushort*)ws; ws += (size_t)8192 * 768 * 2;
    ushort* wqkvt  = (ushort*)ws; ws += (size_t)2304 * 768 * 2;
    ushort* wprojt = (ushort*)ws; ws += (size_t)768  * 768 * 2;
    ushort* qa     = (ushort*)ws; ws += (size_t)96 * 1024 * 64 * 2;
    ushort* ka     = (ushort*)ws; ws += (size_t)96 * 1024 * 64 * 2;
    ushort* vt     = (ushort*)ws; ws += (size_t)96 * 64 * 1024 * 2;
    ushort* ao     = (ushort*)ws; ws += (size_t)8192 * 768 * 2;

    static int attr_set = 0;
    if (!attr_set) {
        hipFuncSetAttribute((const void*)k_qkv,
                            hipFuncAttributeMaxDynamicSharedMemorySize, 139264);
        attr_set = 1;
    }

    k_prep<<<dim3(6720), dim3(256), 0, stream>>>(x, xb, Wqkv, wqkvt, Wproj, wprojt);
    k_qkv<<<dim3(256), dim3(512), 139264, stream>>>(xb, wqkvt, qa, ka, vt);
    k_attn<<<dim3(768), dim3(256), 0, stream>>>(qa, ka, vt, ao);
    k_proj<<<dim3(384), dim3(256), 0, stream>>>(ao, wprojt, out, bproj, 768, 768);
}

// Round 5
// 340.496 us; speedup vs baseline: 1.1343x; 1.0781x over previous
//
#include <hip/hip_runtime.h>
#include <hip/hip_bf16.h>

// LogoAwareAttention: B=8, N=1024, C=768, H=12, Dh=64.
// Per-(b,h) scalar logit bias cancels in softmax -> dropped.
//
// R13 (evidence: R12 VGPR_Count STILL ==128, WRITE 395MB >> 37MB output ->
// accumulator spill persists; two models fit: launch_bounds(512,k) maps
// k->min-blocks (4 waves/EU -> 128 cap), or unified-file 128/128 VGPR/AGPR
// split with acc=144>128. Bank conflicts 2.5M->0: T2 swizzle VERIFIED, kept.
// Fix must satisfy BOTH models):
//  * k_qkv: BM=256 BN=256 (HK's proven per-wave 128x64 -> acc[8][4]=128
//    regs exactly), 8 waves 2Mx4N, __launch_bounds__(512,1) (-> 2 waves/EU
//    -> 256-reg budget under either launch_bounds semantics).
//  * BN=256 => Q/K/V split is BLOCK-uniform (bx 0-2=Q,3-5=K,6-8=V) ->
//    operand-order branch hoisted out of inner loop; epilogue simplifies.
//  * Uniform staging: 2 loads/thread per STA/STB -> exact WAITV(4) at
//    P1/P3 (land oldest k-half, keep newest 4 flying; never 0 mid-loop).
//  * Grid 288 (32x9), XCD map by=xcd*4+s/9 (A-panels pinned per XCD).
//  * LDS 128KB: A[2][2][256][32] then B same, linear dest (gload_lds),
//    T2 involution: global col ^=(row&8)?16:0, ds_read col ^=(m16&8)?16:0.

typedef __bf16 b16x8 __attribute__((ext_vector_type(8)));
typedef float f32x4 __attribute__((ext_vector_type(4)));

__device__ __forceinline__ ushort f2b(float f) {
    union { float f; uint u; } v; v.f = f;
    uint u = v.u;
    u += 0x7fffu + ((u >> 16) & 1u);   // round-to-nearest-even
    return (ushort)(u >> 16);
}

__device__ __forceinline__ uint packbf(float a, float b) {
    union { float f; uint u; } ua, ub; ua.f = a; ub.f = b;
    return ((ua.u + 0x8000u) >> 16) | ((ub.u + 0x8000u) & 0xffff0000u);
}

// async 16B-per-lane global->LDS copy; lds dest = wave-uniform base + lane*16
__device__ __forceinline__ void async_cp16(const void* g, void* l) {
    __builtin_amdgcn_global_load_lds(
        (const __attribute__((address_space(1))) unsigned int*)g,
        (__attribute__((address_space(3))) unsigned int*)l, 16, 0, 0);
}

// ---------------- fused prep: x->bf16 | Wqkv^T | Wproj^T ----------------
// blocks [0,6144): conv;  [6144,6576): Wqkv transpose;  [6576,6720): Wproj.

__global__ __launch_bounds__(256)
void k_prep(const float* __restrict__ x, ushort* __restrict__ xb,
            const float* __restrict__ Wqkv, ushort* __restrict__ wqkvt,
            const float* __restrict__ Wproj, ushort* __restrict__ wprojt) {
    __shared__ ushort T[64][65];
    const int blk = blockIdx.x;
    const int t   = threadIdx.x;

    if (blk < 6144) {
        const int i = blk * 256 + t;
        const float4 v = reinterpret_cast<const float4*>(x)[i];
        ushort4 o;
        o.x = f2b(v.x); o.y = f2b(v.y); o.z = f2b(v.z); o.w = f2b(v.w);
        reinterpret_cast<ushort4*>(xb)[i] = o;
        return;
    }

    const bool isqkv = (blk < 6576);
    const int idx = isqkv ? (blk - 6144) : (blk - 6576);
    const int Nin = isqkv ? 2304 : 768;
    const float* W  = isqkv ? Wqkv : Wproj;
    ushort* Wt      = isqkv ? wqkvt : wprojt;
    const int k0 = (idx % 12) * 64;
    const int n0 = (idx / 12) * 64;
    const int r  = t >> 4, cg = (t & 15) * 4;
    #pragma unroll
    for (int rr = 0; rr < 64; rr += 16) {
        const float4 v = *reinterpret_cast<const float4*>(&W[(size_t)(k0 + r + rr) * Nin + n0 + cg]);
        T[r + rr][cg + 0] = f2b(v.x); T[r + rr][cg + 1] = f2b(v.y);
        T[r + rr][cg + 2] = f2b(v.z); T[r + rr][cg + 3] = f2b(v.w);
    }
    __syncthreads();
    #pragma unroll
    for (int rr = 0; rr < 64; rr += 16) {
        ushort4 o;
        o.x = T[cg + 0][r + rr]; o.y = T[cg + 1][r + rr];
        o.z = T[cg + 2][r + rr]; o.w = T[cg + 3][r + rr];
        *reinterpret_cast<ushort4*>(&Wt[(size_t)(n0 + r + rr) * 768 + k0 + cg]) = o;
    }
}

// ---------------- k_qkv: 256x256 tile, BK=64, 8 waves, 4-phase pipeline ----------

#define SBAR()   asm volatile("s_barrier" ::: "memory")
#define WAITV4() asm volatile("s_waitcnt vmcnt(4)" ::: "memory")
#define WAITV0() asm volatile("s_waitcnt vmcnt(0)" ::: "memory")

// LDS (ushort elems): A[buf] at buf*16384, B[buf] at 32768+buf*16384;
// within: kh*8192 + row*32 + col  (row = slot*128 + w*16 + (lane>>2)).
#define LDSA(buf, kh, ii) (*reinterpret_cast<const b16x8*>( \
    &lds[(buf) * 16384 + (kh) * 8192 + (wm * 128 + (ii) * 16 + m16) * 32 + q8s]))
#define LDSB(buf, kh, jj) (*reinterpret_cast<const b16x8*>( \
    &lds[32768 + (buf) * 16384 + (kh) * 8192 + (wn * 64 + (jj) * 16 + m16) * 32 + q8s]))

// stage one k-half: 2 uniform loads/thread each (slot 0 / slot 1)
#define STA(bufn, ktv, kh) { \
    async_cp16(aA0 + (ktv) + (kh) * 32, &lds[(bufn)*16384 + (kh)*8192 + 0*4096 + w*512]); \
    async_cp16(aA1 + (ktv) + (kh) * 32, &lds[(bufn)*16384 + (kh)*8192 + 1*4096 + w*512]); }
#define STB(bufn, ktv, kh) { \
    async_cp16(aB0 + (ktv) + (kh) * 32, &lds[32768 + (bufn)*16384 + (kh)*8192 + 0*4096 + w*512]); \
    async_cp16(aB1 + (ktv) + (kh) * 32, &lds[32768 + (bufn)*16384 + (kh)*8192 + 1*4096 + w*512]); }

// 16 MFMA: m-quad (I0..I0+3) x 4 n-frags x one k-half. vblk (block-uniform):
// V unswapped (lane=feature-major), Q/K swapped (lane=token-major).
#define QUAD(I0, kh, bufc) { \
    const b16x8 a0 = LDSA(bufc, kh, (I0)+0), a1 = LDSA(bufc, kh, (I0)+1); \
    const b16x8 a2 = LDSA(bufc, kh, (I0)+2), a3 = LDSA(bufc, kh, (I0)+3); \
    if (vblk) { \
        _Pragma("unroll") \
        for (int j = 0; j < 4; j++) { \
            acc[(I0)+0][j] = __builtin_amdgcn_mfma_f32_16x16x32_bf16(a0, bf[j], acc[(I0)+0][j], 0, 0, 0); \
            acc[(I0)+1][j] = __builtin_amdgcn_mfma_f32_16x16x32_bf16(a1, bf[j], acc[(I0)+1][j], 0, 0, 0); \
            acc[(I0)+2][j] = __builtin_amdgcn_mfma_f32_16x16x32_bf16(a2, bf[j], acc[(I0)+2][j], 0, 0, 0); \
            acc[(I0)+3][j] = __builtin_amdgcn_mfma_f32_16x16x32_bf16(a3, bf[j], acc[(I0)+3][j], 0, 0, 0); \
        } \
    } else { \
        _Pragma("unroll") \
        for (int j = 0; j < 4; j++) { \
            acc[(I0)+0][j] = __builtin_amdgcn_mfma_f32_16x16x32_bf16(bf[j], a0, acc[(I0)+0][j], 0, 0, 0); \
            acc[(I0)+1][j] = __builtin_amdgcn_mfma_f32_16x16x32_bf16(bf[j], a1, acc[(I0)+1][j], 0, 0, 0); \
            acc[(I0)+2][j] = __builtin_amdgcn_mfma_f32_16x16x32_bf16(bf[j], a2, acc[(I0)+2][j], 0, 0, 0); \
            acc[(I0)+3][j] = __builtin_amdgcn_mfma_f32_16x16x32_bf16(bf[j], a3, acc[(I0)+3][j], 0, 0, 0); \
        } \
    } }

__global__ __launch_bounds__(512, 1)
void k_qkv(const ushort* __restrict__ A, const ushort* __restrict__ Bt,
           ushort* __restrict__ qo, ushort* __restrict__ ko,
           ushort* __restrict__ vo) {
    extern __shared__ ushort lds[];
    const int id   = blockIdx.x;           // 0..287
    const int xcd  = id & 7;
    const int s    = id >> 3;              // 0..35
    const int by   = xcd * 4 + s / 9;      // 4 A-panels pinned per XCD
    const int bx   = s % 9;                // 0..8 (0-2=Q, 3-5=K, 6-8=V)
    const int tid  = threadIdx.x;
    const int w    = tid >> 6;             // 8 waves
    const int lane = tid & 63;
    const int wm   = w >> 2, wn = w & 3;   // 2M x 4N -> per-wave 128x64
    const int m16  = lane & 15, quad = lane >> 4;
    const int q8   = quad * 8;
    const int q8s  = q8 ^ ((m16 & 8) ? 16 : 0);     // T2 read-side XOR
    const int mbase = by * 256, nbase = bx * 256;
    const int colbase = nbase + wn * 64;
    const bool vblk = (nbase >= 1536);
    const int lr   = lane >> 2;
    const int ssub = ((lane & 3) * 8) ^ ((lr & 8) ? 16 : 0);  // T2 source XOR

    // per-thread staging base pointers (slot 0 = rows 0..127, slot 1 = +128)
    const ushort* aA0 = &A [(size_t)(mbase +       w * 16 + lr) * 768 + ssub];
    const ushort* aA1 = &A [(size_t)(mbase + 128 + w * 16 + lr) * 768 + ssub];
    const ushort* aB0 = &Bt[(size_t)(nbase +       w * 16 + lr) * 768 + ssub];
    const ushort* aB1 = &Bt[(size_t)(nbase + 128 + w * 16 + lr) * 768 + ssub];

    f32x4 acc[8][4];
    #pragma unroll
    for (int i = 0; i < 8; i++)
        #pragma unroll
        for (int j = 0; j < 4; j++) acc[i][j] = (f32x4){0.f, 0.f, 0.f, 0.f};

    // prologue: tile 0 both k-halves (8 loads); land k0, keep k1 flying
    STA(0, 0, 0); STB(0, 0, 0);
    STA(0, 0, 1); STB(0, 0, 1);
    WAITV4();
    SBAR();

    b16x8 bf[4];
    int cur = 0;
    for (int t = 0; t < 12; t++) {
        const int kt  = t * 64;
        const int nxt = cur ^ 1;
        const bool more = (t < 11);
        // P0: read B(k0); stage A(t+1,k0); MFMA m0-3 x k0
        #pragma unroll
        for (int j = 0; j < 4; j++) bf[j] = LDSB(cur, 0, j);
        if (more) STA(nxt, kt + 64, 0);
        __builtin_amdgcn_s_setprio(1);
        QUAD(0, 0, cur);
        __builtin_amdgcn_s_setprio(0);
        SBAR();
        // P1: stage B(t+1,k0); MFMA m4-7 x k0; land cur-k1 (keep t+1-k0)
        if (more) STB(nxt, kt + 64, 0);
        __builtin_amdgcn_s_setprio(1);
        QUAD(4, 0, cur);
        __builtin_amdgcn_s_setprio(0);
        if (more) { WAITV4(); } else { WAITV0(); }
        SBAR();
        // P2: read B(k1); stage A(t+1,k1); MFMA m0-3 x k1
        #pragma unroll
        for (int j = 0; j < 4; j++) bf[j] = LDSB(cur, 1, j);
        if (more) STA(nxt, kt + 64, 1);
        __builtin_amdgcn_s_setprio(1);
        QUAD(0, 1, cur);
        __builtin_amdgcn_s_setprio(0);
        SBAR();
        // P3: stage B(t+1,k1); MFMA m4-7 x k1; land t+1-k0 (keep t+1-k1)
        if (more) STB(nxt, kt + 64, 1);
        __builtin_amdgcn_s_setprio(1);
        QUAD(4, 1, cur);
        __builtin_amdgcn_s_setprio(0);
        if (more) {
            WAITV4();
            SBAR();
        }
        cur = nxt;
    }

    // epilogue (block-uniform kind)
    if (vblk) {
        // unswapped: lane holds 4 consecutive tokens (quad*4+r) of feature colbase+j*16+m16
        #pragma unroll
        for (int j = 0; j < 4; j++) {
            const int rem = colbase + j * 16 + m16 - 1536;
            const int h = rem >> 6, d0 = rem & 63;
            #pragma unroll
            for (int i = 0; i < 8; i++) {
                const int tok0 = mbase + wm * 128 + i * 16 + quad * 4;
                const int b = tok0 >> 10, n0 = tok0 & 1023;
                ushort4 pk;
                pk.x = f2b(acc[i][j][0]); pk.y = f2b(acc[i][j][1]);
                pk.z = f2b(acc[i][j][2]); pk.w = f2b(acc[i][j][3]);
                *reinterpret_cast<ushort4*>(
                    &vo[((size_t)(b * 12 + h) * 64 + d0) * 1024 + n0]) = pk;
            }
        }
    } else {
        // swapped: lane holds 4 consecutive features (quad*4+r) of token row+m16
        ushort* base  = (nbase >= 768) ? ko : qo;
        const int off = (nbase >= 768) ? 768 : 0;
        #pragma unroll
        for (int j = 0; j < 4; j++) {
            const int f0 = colbase + j * 16 + quad * 4 - off;
            const int h = f0 >> 6, d0 = f0 & 63;
            #pragma unroll
            for (int i = 0; i < 8; i++) {
                const int tok = mbase + wm * 128 + i * 16 + m16;
                const int b = tok >> 10, n = tok & 1023;
                ushort4 pk;
                pk.x = f2b(acc[i][j][0]); pk.y = f2b(acc[i][j][1]);
                pk.z = f2b(acc[i][j][2]); pk.w = f2b(acc[i][j][3]);
                *reinterpret_cast<ushort4*>(
                    &base[((size_t)(b * 12 + h) * 1024 + n) * 64 + d0]) = pk;
            }
        }
    }
}

// ---------------- k_proj: R8-baseline 128x128, BK=32, dbuf, f32+bias out ----------

__global__ __launch_bounds__(256, 2)
void k_proj(const ushort* __restrict__ A, const ushort* __restrict__ Bt,
            float* __restrict__ co, const float* __restrict__ bias,
            int N, int K) {
    __shared__ ushort As[2][128 * 32];
    __shared__ ushort Bs[2][128 * 32];
    const int id   = blockIdx.x;
    const int xcd  = id & 7;
    const int s    = id >> 3;
    const int by   = xcd * 8 + (s & 7);
    const int bx   = s >> 3;
    const int tid  = threadIdx.x;
    const int lane = tid & 63;
    const int w    = tid >> 6;
    const int wm   = w >> 1, wn = w & 1;
    const int m16  = lane & 15, quad = lane >> 4;
    const int mbase = by * 128, nbase = bx * 128;

    f32x4 acc[4][4];
    #pragma unroll
    for (int i = 0; i < 4; i++)
        #pragma unroll
        for (int j = 0; j < 4; j++) acc[i][j] = (f32x4){0.f, 0.f, 0.f, 0.f};

    const int rS = w * 32 + (lane >> 2);
    const int cS = (lane & 3) * 8;
    const int wOff0 = (w * 2 + 0) * 512;
    const int wOff1 = (w * 2 + 1) * 512;
    const ushort* gA0 = &A [(size_t)(mbase + rS)      * K + cS];
    const ushort* gA1 = &A [(size_t)(mbase + rS + 16) * K + cS];
    const ushort* gB0 = &Bt[(size_t)(nbase + rS)      * K + cS];
    const ushort* gB1 = &Bt[(size_t)(nbase + rS + 16) * K + cS];

    async_cp16(gA0, &As[0][wOff0]);
    async_cp16(gA1, &As[0][wOff1]);
    async_cp16(gB0, &Bs[0][wOff0]);
    async_cp16(gB1, &Bs[0][wOff1]);

    for (int kt = 0; kt < K; kt += 32) {
        const int cur = (kt >> 5) & 1, nxt = cur ^ 1;
        __syncthreads();
        if (kt + 32 < K) {
            async_cp16(gA0 + kt + 32, &As[nxt][wOff0]);
            async_cp16(gA1 + kt + 32, &As[nxt][wOff1]);
            async_cp16(gB0 + kt + 32, &Bs[nxt][wOff0]);
            async_cp16(gB1 + kt + 32, &Bs[nxt][wOff1]);
        }
        b16x8 af[4], bfr[4];
        #pragma unroll
        for (int i = 0; i < 4; i++)
            af[i] = *reinterpret_cast<const b16x8*>(&As[cur][(wm * 64 + i * 16 + m16) * 32 + quad * 8]);
        #pragma unroll
        for (int j = 0; j < 4; j++)
            bfr[j] = *reinterpret_cast<const b16x8*>(&Bs[cur][(wn * 64 + j * 16 + m16) * 32 + quad * 8]);
        #pragma unroll
        for (int i = 0; i < 4; i++)
            #pragma unroll
            for (int j = 0; j < 4; j++)
                acc[i][j] = __builtin_amdgcn_mfma_f32_16x16x32_bf16(bfr[j], af[i], acc[i][j], 0, 0, 0);
    }

    #pragma unroll
    for (int j = 0; j < 4; j++) {
        const int f0 = nbase + wn * 64 + j * 16 + quad * 4;
        #pragma unroll
        for (int i = 0; i < 4; i++) {
            const int tok = mbase + wm * 64 + i * 16 + m16;
            float4 val;
            val.x = acc[i][j][0] + bias[f0 + 0];
            val.y = acc[i][j][1] + bias[f0 + 1];
            val.z = acc[i][j][2] + bias[f0 + 2];
            val.w = acc[i][j][3] + bias[f0 + 3];
            *reinterpret_cast<float4*>(&co[(size_t)tok * N + f0]) = val;
        }
    }
}

// ---------------- attention: flash, LDS-staged K/V, Q-blocked x2 (unchanged) ----------

#define AP 72   // LDS row pitch (elements)

__global__ __launch_bounds__(256)
void k_attn(const ushort* __restrict__ qa, const ushort* __restrict__ ka,
            const ushort* __restrict__ vt, ushort* __restrict__ ao) {
    __shared__ ushort Ks[64 * AP];
    __shared__ ushort Vs[64 * AP];

    const int l    = blockIdx.x;               // 0..767
    const int xcd  = l & 7;
    const int g    = l >> 3;                   // 0..95
    const int head = (g % 12) * 8 + xcd;       // head%8 == xcd -> XCD locality
    const int qsup = g / 12;                   // 0..7 (128-row supertile)
    const int tid  = threadIdx.x;
    const int w    = tid >> 6;
    const int lane = tid & 63;
    const int n    = lane & 15;
    const int q    = lane >> 4;

    const ushort* qh = qa + (size_t)head * 65536;
    const ushort* kh = ka + (size_t)head * 65536;
    const ushort* vh = vt + (size_t)head * 65536;
    const int qrow0 = qsup * 128 + w * 32;

    b16x8 bq0[2], bq1[2];
    #pragma unroll
    for (int u = 0; u < 2; u++) {
        bq0[u] = *reinterpret_cast<const b16x8*>(&qh[(qrow0 + u * 16 + n) * 64 + q * 8]);
        bq1[u] = *reinterpret_cast<const b16x8*>(&qh[(qrow0 + u * 16 + n) * 64 + 32 + q * 8]);
    }

    const int kr0 = tid >> 3, kc0 = (tid & 7) * 8;
    const int kr1 = kr0 + 32, kc1 = kc0;

    int4 kg0, kg1, vg0, vg1;
    kg0 = *reinterpret_cast<const int4*>(&kh[(0 + kr0) * 64 + kc0]);
    kg1 = *reinterpret_cast<const int4*>(&kh[(0 + kr1) * 64 + kc1]);
    vg0 = *reinterpret_cast<const int4*>(&vh[kr0 * 1024 + 0 + kc0]);
    vg1 = *reinterpret_cast<const int4*>(&vh[kr1 * 1024 + 0 + kc1]);

    f32x4 o[2][4];
    #pragma unroll
    for (int u = 0; u < 2; u++)
        #pragma unroll
        for (int dt = 0; dt < 4; dt++) o[u][dt] = (f32x4){0, 0, 0, 0};
    float Lacc[2] = {0.f, 0.f};

    const float SC = 0.125f * 1.4426950408889634f;
    const int s0 = ((q & 1) * 2) * 16 + n;
    const int s1 = s0 + 16;
    const bool lowq = (q < 2);

    for (int m0 = 0; m0 < 1024; m0 += 64) {
        *reinterpret_cast<int4*>(&Ks[kr0 * AP + kc0]) = kg0;
        *reinterpret_cast<int4*>(&Ks[kr1 * AP + kc1]) = kg1;
        *reinterpret_cast<int4*>(&Vs[kr0 * AP + kc0]) = vg0;
        *reinterpret_cast<int4*>(&Vs[kr1 * AP + kc1]) = vg1;
        __syncthreads();

        if (m0 + 64 < 1024) {
            kg0 = *reinterpret_cast<const int4*>(&kh[(m0 + 64 + kr0) * 64 + kc0]);
            kg1 = *reinterpret_cast<const int4*>(&kh[(m0 + 64 + kr1) * 64 + kc1]);
            vg0 = *reinterpret_cast<const int4*>(&vh[kr0 * 1024 + m0 + 64 + kc0]);
            vg1 = *reinterpret_cast<const int4*>(&vh[kr1 * 1024 + m0 + 64 + kc1]);
        }

        #pragma unroll
        for (int mc = 0; mc < 2; mc++) {
            b16x8 ka0t[2], ka1t[2];
            #pragma unroll
            for (int t = 0; t < 2; t++) {
                ka0t[t] = *reinterpret_cast<const b16x8*>(&Ks[(mc * 32 + t * 16 + n) * AP + q * 8]);
                ka1t[t] = *reinterpret_cast<const b16x8*>(&Ks[(mc * 32 + t * 16 + n) * AP + 32 + q * 8]);
            }
            f32x4 st[2][2];
            #pragma unroll
            for (int u = 0; u < 2; u++)
                #pragma unroll
                for (int t = 0; t < 2; t++) {
                    st[u][t] = (f32x4){0, 0, 0, 0};
                    st[u][t] = __builtin_amdgcn_mfma_f32_16x16x32_bf16(ka0t[t], bq0[u], st[u][t], 0, 0, 0);
                    st[u][t] = __builtin_amdgcn_mfma_f32_16x16x32_bf16(ka1t[t], bq1[u], st[u][t], 0, 0, 0);
                }

            union { uint4 u4; b16x8 v; } bp[2];
            #pragma unroll
            for (int u = 0; u < 2; u++) {
                float p00 = __builtin_amdgcn_exp2f(st[u][0][0] * SC);
                float p01 = __builtin_amdgcn_exp2f(st[u][0][1] * SC);
                float p02 = __builtin_amdgcn_exp2f(st[u][0][2] * SC);
                float p03 = __builtin_amdgcn_exp2f(st[u][0][3] * SC);
                float p10 = __builtin_amdgcn_exp2f(st[u][1][0] * SC);
                float p11 = __builtin_amdgcn_exp2f(st[u][1][1] * SC);
                float p12 = __builtin_amdgcn_exp2f(st[u][1][2] * SC);
                float p13 = __builtin_amdgcn_exp2f(st[u][1][3] * SC);
                Lacc[u] += ((p00 + p01) + (p02 + p03)) + ((p10 + p11) + (p12 + p13));

                const uint pk00 = packbf(p00, p01), pk01 = packbf(p02, p03);
                const uint pk10 = packbf(p10, p11), pk11 = packbf(p12, p13);

                uint a, b, dw0, dw1, dw2, dw3;
                a = __shfl((int)pk00, s0); b = __shfl((int)pk10, s0); dw0 = lowq ? a : b;
                a = __shfl((int)pk01, s0); b = __shfl((int)pk11, s0); dw1 = lowq ? a : b;
                a = __shfl((int)pk00, s1); b = __shfl((int)pk10, s1); dw2 = lowq ? a : b;
                a = __shfl((int)pk01, s1); b = __shfl((int)pk11, s1); dw3 = lowq ? a : b;
                bp[u].u4 = (uint4){dw0, dw1, dw2, dw3};
            }

            #pragma unroll
            for (int dt = 0; dt < 4; dt++) {
                const b16x8 av = *reinterpret_cast<const b16x8*>(
                    &Vs[(dt * 16 + n) * AP + mc * 32 + q * 8]);
                #pragma unroll
                for (int u = 0; u < 2; u++)
                    o[u][dt] = __builtin_amdgcn_mfma_f32_16x16x32_bf16(av, bp[u].v, o[u][dt], 0, 0, 0);
            }
        }
        __syncthreads();
    }

    const int bb = head / 12, h = head - bb * 12;
    #pragma unroll
    for (int u = 0; u < 2; u++) {
        float L = Lacc[u];
        L += __shfl_xor(L, 16);
        L += __shfl_xor(L, 32);
        const float inv = 1.f / L;
        ushort* dst = ao + ((size_t)(bb * 1024 + qrow0 + u * 16 + n)) * 768 + h * 64 + q * 4;
        #pragma unroll
        for (int dt = 0; dt < 4; dt++) {
            ushort4 pk;
            pk.x = f2b(o[u][dt][0] * inv);
            pk.y = f2b(o[u][dt][1] * inv);
            pk.z = f2b(o[u][dt][2] * inv);
            pk.w = f2b(o[u][dt][3] * inv);
            *reinterpret_cast<ushort4*>(dst + dt * 16) = pk;
        }
    }
}

// ---------------- launch ----------------

extern "C" void kernel_launch(void* const* d_in, const int* in_sizes, int n_in,
                              void* d_out, int out_size, void* d_ws, size_t ws_size,
                              hipStream_t stream) {
    (void)in_sizes; (void)n_in; (void)out_size; (void)ws_size;
    const float* x     = (const float*)d_in[0];
    const float* Wqkv  = (const float*)d_in[4];
    const float* Wproj = (const float*)d_in[5];
    const float* bproj = (const float*)d_in[6];
    float* out = (float*)d_out;

    char* ws = (char*)d_ws;
    ushort* xb     = (ushort*)ws; ws += (size_t)8192 * 768 * 2;
    ushort* wqkvt  = (ushort*)ws; ws += (size_t)2304 * 768 * 2;
    ushort* wprojt = (ushort*)ws; ws += (size_t)768  * 768 * 2;
    ushort* qa     = (ushort*)ws; ws += (size_t)96 * 1024 * 64 * 2;
    ushort* ka     = (ushort*)ws; ws += (size_t)96 * 1024 * 64 * 2;
    ushort* vt     = (ushort*)ws; ws += (size_t)96 * 64 * 1024 * 2;
    ushort* ao     = (ushort*)ws; ws += (size_t)8192 * 768 * 2;

    static int attr_set = 0;
    if (!attr_set) {
        hipFuncSetAttribute((const void*)k_qkv,
                            hipFuncAttributeMaxDynamicSharedMemorySize, 131072);
        attr_set = 1;
    }

    k_prep<<<dim3(6720), dim3(256), 0, stream>>>(x, xb, Wqkv, wqkvt, Wproj, wprojt);
    k_qkv<<<dim3(288), dim3(512), 131072, stream>>>(xb, wqkvt, qa, ka, vt);
    k_attn<<<dim3(768), dim3(256), 0, stream>>>(qa, ka, vt, ao);
    k_proj<<<dim3(384), dim3(256), 0, stream>>>(ao, wprojt, out, bproj, 768, 768);
}

// Round 6
// 224.164 us; speedup vs baseline: 1.7229x; 1.5190x over previous
//
#include <hip/hip_runtime.h>
#include <hip/hip_bf16.h>

// LogoAwareAttention: B=8, N=1024, C=768, H=12, Dh=64.
// Per-(b,h) scalar logit bias cancels in softmax -> dropped.
//
// R14 (evidence: VGPR_Count==128 in R11/R12/R13 under THREE different
// launch-bounds spellings -> treat 128 as a hard cap for 512-thr dynamic-LDS
// kernels and design UNDER it. R13 banked: T2 swizzle=0 conflicts, 4-phase
// counted-vmcnt correctness, FETCH ~ideal. Only pathology left = spill):
//  * k_qkv: BM=256 BN=128 BK=64, 8 waves 4Mx2N -> per-wave 64x64,
//    acc[4][4]=64 regs; total demand ~110 < 128 -> fits under the cap.
//  * Uniform staging: 3 loads/thread per k-half (A:2, B:1) -> exact
//    WAITV(3) stagger, never 0 mid-loop, no per-wave special cases.
//  * Grid 576 (32x18): A panels XCD-pinned (by=xcd*4+s/18); Q/K/V
//    block-uniform (bx 0-5 Q, 6-11 K, 12-17 V). Known ~2.25-round tail,
//    still ~2x faster than the R8 2-phase baseline by arithmetic.
//  * LDS 96KB dynamic dbuf; T2 involution (source col ^ row-bit3, read
//    col ^ m16-bit3), linear gload_lds dest. 4-phase schedule + setprio.

typedef __bf16 b16x8 __attribute__((ext_vector_type(8)));
typedef float f32x4 __attribute__((ext_vector_type(4)));

__device__ __forceinline__ ushort f2b(float f) {
    union { float f; uint u; } v; v.f = f;
    uint u = v.u;
    u += 0x7fffu + ((u >> 16) & 1u);   // round-to-nearest-even
    return (ushort)(u >> 16);
}

__device__ __forceinline__ uint packbf(float a, float b) {
    union { float f; uint u; } ua, ub; ua.f = a; ub.f = b;
    return ((ua.u + 0x8000u) >> 16) | ((ub.u + 0x8000u) & 0xffff0000u);
}

// async 16B-per-lane global->LDS copy; lds dest = wave-uniform base + lane*16
__device__ __forceinline__ void async_cp16(const void* g, void* l) {
    __builtin_amdgcn_global_load_lds(
        (const __attribute__((address_space(1))) unsigned int*)g,
        (__attribute__((address_space(3))) unsigned int*)l, 16, 0, 0);
}

// ---------------- fused prep: x->bf16 | Wqkv^T | Wproj^T ----------------
// blocks [0,6144): conv;  [6144,6576): Wqkv transpose;  [6576,6720): Wproj.

__global__ __launch_bounds__(256)
void k_prep(const float* __restrict__ x, ushort* __restrict__ xb,
            const float* __restrict__ Wqkv, ushort* __restrict__ wqkvt,
            const float* __restrict__ Wproj, ushort* __restrict__ wprojt) {
    __shared__ ushort T[64][65];
    const int blk = blockIdx.x;
    const int t   = threadIdx.x;

    if (blk < 6144) {
        const int i = blk * 256 + t;
        const float4 v = reinterpret_cast<const float4*>(x)[i];
        ushort4 o;
        o.x = f2b(v.x); o.y = f2b(v.y); o.z = f2b(v.z); o.w = f2b(v.w);
        reinterpret_cast<ushort4*>(xb)[i] = o;
        return;
    }

    const bool isqkv = (blk < 6576);
    const int idx = isqkv ? (blk - 6144) : (blk - 6576);
    const int Nin = isqkv ? 2304 : 768;
    const float* W  = isqkv ? Wqkv : Wproj;
    ushort* Wt      = isqkv ? wqkvt : wprojt;
    const int k0 = (idx % 12) * 64;
    const int n0 = (idx / 12) * 64;
    const int r  = t >> 4, cg = (t & 15) * 4;
    #pragma unroll
    for (int rr = 0; rr < 64; rr += 16) {
        const float4 v = *reinterpret_cast<const float4*>(&W[(size_t)(k0 + r + rr) * Nin + n0 + cg]);
        T[r + rr][cg + 0] = f2b(v.x); T[r + rr][cg + 1] = f2b(v.y);
        T[r + rr][cg + 2] = f2b(v.z); T[r + rr][cg + 3] = f2b(v.w);
    }
    __syncthreads();
    #pragma unroll
    for (int rr = 0; rr < 64; rr += 16) {
        ushort4 o;
        o.x = T[cg + 0][r + rr]; o.y = T[cg + 1][r + rr];
        o.z = T[cg + 2][r + rr]; o.w = T[cg + 3][r + rr];
        *reinterpret_cast<ushort4*>(&Wt[(size_t)(n0 + r + rr) * 768 + k0 + cg]) = o;
    }
}

// ---------------- k_qkv: 256x128 tile, BK=64, 8 waves, 4-phase pipeline ----------

#define SBAR()   asm volatile("s_barrier" ::: "memory")
#define WAITV3() asm volatile("s_waitcnt vmcnt(3)" ::: "memory")
#define WAITV0() asm volatile("s_waitcnt vmcnt(0)" ::: "memory")

// LDS (ushort elems): A[buf][kh] at buf*16384 + kh*8192 (256x32 each);
// B[buf][kh] at 32768 + buf*8192 + kh*4096 (128x32 each). Total 96KB.
#define LDSA(buf, kh, ii) (*reinterpret_cast<const b16x8*>( \
    &lds[(buf) * 16384 + (kh) * 8192 + (wm * 64 + (ii) * 16 + m16) * 32 + q8s]))
#define LDSB(buf, kh, jj) (*reinterpret_cast<const b16x8*>( \
    &lds[32768 + (buf) * 8192 + (kh) * 4096 + (wn * 64 + (jj) * 16 + m16) * 32 + q8s]))

// stage one k-half: A 2 loads/thread, B 1 load/thread (uniform: 3 total)
#define STA(bufn, ktv, kh) { \
    async_cp16(aA0 + (ktv) + (kh) * 32, &lds[(bufn)*16384 + (kh)*8192 + tid*8]); \
    async_cp16(aA1 + (ktv) + (kh) * 32, &lds[(bufn)*16384 + (kh)*8192 + 4096 + tid*8]); }
#define STB(bufn, ktv, kh) { \
    async_cp16(aB0 + (ktv) + (kh) * 32, &lds[32768 + (bufn)*8192 + (kh)*4096 + tid*8]); }

// 8 MFMA: m-pair (I0,I0+1) x 4 n-frags x one k-half. Block-uniform vblk:
// V unswapped (lane=feature-major), Q/K swapped (lane=token-major).
#define MPAIR(I0, kh, bufc) { \
    const b16x8 a0 = LDSA(bufc, kh, (I0)+0), a1 = LDSA(bufc, kh, (I0)+1); \
    if (vblk) { \
        _Pragma("unroll") \
        for (int j = 0; j < 4; j++) { \
            acc[(I0)+0][j] = __builtin_amdgcn_mfma_f32_16x16x32_bf16(a0, bf[j], acc[(I0)+0][j], 0, 0, 0); \
            acc[(I0)+1][j] = __builtin_amdgcn_mfma_f32_16x16x32_bf16(a1, bf[j], acc[(I0)+1][j], 0, 0, 0); \
        } \
    } else { \
        _Pragma("unroll") \
        for (int j = 0; j < 4; j++) { \
            acc[(I0)+0][j] = __builtin_amdgcn_mfma_f32_16x16x32_bf16(bf[j], a0, acc[(I0)+0][j], 0, 0, 0); \
            acc[(I0)+1][j] = __builtin_amdgcn_mfma_f32_16x16x32_bf16(bf[j], a1, acc[(I0)+1][j], 0, 0, 0); \
        } \
    } }

__global__ __launch_bounds__(512, 1)
void k_qkv(const ushort* __restrict__ A, const ushort* __restrict__ Bt,
           ushort* __restrict__ qo, ushort* __restrict__ ko,
           ushort* __restrict__ vo) {
    extern __shared__ ushort lds[];
    const int id   = blockIdx.x;           // 0..575
    const int xcd  = id & 7;
    const int s    = id >> 3;              // 0..71
    const int by   = xcd * 4 + s / 18;     // 4 A-panels pinned per XCD
    const int bx   = s % 18;               // 0..17 (0-5=Q, 6-11=K, 12-17=V)
    const int tid  = threadIdx.x;
    const int w    = tid >> 6;             // 8 waves
    const int lane = tid & 63;
    const int wm   = w >> 1, wn = w & 1;   // 4M x 2N -> per-wave 64x64
    const int m16  = lane & 15, quad = lane >> 4;
    const int q8   = quad * 8;
    const int q8s  = q8 ^ ((m16 & 8) ? 16 : 0);     // T2 read-side XOR
    const int mbase = by * 256, nbase = bx * 128;
    const int colbase = nbase + wn * 64;
    const bool vblk = (nbase >= 1536);
    const int tr   = tid >> 2;             // staging row 0..127
    const int ssub = ((tid & 3) * 8) ^ ((tr & 8) ? 16 : 0);  // T2 source XOR

    // per-thread staging base pointers
    const ushort* aA0 = &A [(size_t)(mbase +       tr) * 768 + ssub];
    const ushort* aA1 = &A [(size_t)(mbase + 128 + tr) * 768 + ssub];
    const ushort* aB0 = &Bt[(size_t)(nbase +       tr) * 768 + ssub];

    f32x4 acc[4][4];
    #pragma unroll
    for (int i = 0; i < 4; i++)
        #pragma unroll
        for (int j = 0; j < 4; j++) acc[i][j] = (f32x4){0.f, 0.f, 0.f, 0.f};

    // prologue: tile 0 both k-halves (6 loads/thread); land k0, keep k1 flying
    STA(0, 0, 0); STB(0, 0, 0);
    STA(0, 0, 1); STB(0, 0, 1);
    WAITV3();
    SBAR();

    b16x8 bf[4];
    int cur = 0;
    for (int t = 0; t < 12; t++) {
        const int kt  = t * 64;
        const int nxt = cur ^ 1;
        const bool more = (t < 11);
        // P0: read B(k0); stage A(t+1,k0); MFMA m01 x k0
        #pragma unroll
        for (int j = 0; j < 4; j++) bf[j] = LDSB(cur, 0, j);
        if (more) STA(nxt, kt + 64, 0);
        __builtin_amdgcn_s_setprio(1);
        MPAIR(0, 0, cur);
        __builtin_amdgcn_s_setprio(0);
        SBAR();
        // P1: stage B(t+1,k0); MFMA m23 x k0; land cur-k1 (keep nxt-k0)
        if (more) STB(nxt, kt + 64, 0);
        __builtin_amdgcn_s_setprio(1);
        MPAIR(2, 0, cur);
        __builtin_amdgcn_s_setprio(0);
        if (more) { WAITV3(); } else { WAITV0(); }
        SBAR();
        // P2: read B(k1); stage A(t+1,k1); MFMA m01 x k1
        #pragma unroll
        for (int j = 0; j < 4; j++) bf[j] = LDSB(cur, 1, j);
        if (more) STA(nxt, kt + 64, 1);
        __builtin_amdgcn_s_setprio(1);
        MPAIR(0, 1, cur);
        __builtin_amdgcn_s_setprio(0);
        SBAR();
        // P3: stage B(t+1,k1); MFMA m23 x k1; land nxt-k0 (keep nxt-k1)
        if (more) STB(nxt, kt + 64, 1);
        __builtin_amdgcn_s_setprio(1);
        MPAIR(2, 1, cur);
        __builtin_amdgcn_s_setprio(0);
        if (more) {
            WAITV3();
            SBAR();
        }
        cur = nxt;
    }

    // epilogue (block-uniform kind)
    if (vblk) {
        // unswapped: lane holds 4 consecutive tokens (quad*4+r) of feature colbase+j*16+m16
        #pragma unroll
        for (int j = 0; j < 4; j++) {
            const int rem = colbase + j * 16 + m16 - 1536;
            const int h = rem >> 6, d0 = rem & 63;
            #pragma unroll
            for (int i = 0; i < 4; i++) {
                const int tok0 = mbase + wm * 64 + i * 16 + quad * 4;
                const int b = tok0 >> 10, n0 = tok0 & 1023;
                ushort4 pk;
                pk.x = f2b(acc[i][j][0]); pk.y = f2b(acc[i][j][1]);
                pk.z = f2b(acc[i][j][2]); pk.w = f2b(acc[i][j][3]);
                *reinterpret_cast<ushort4*>(
                    &vo[((size_t)(b * 12 + h) * 64 + d0) * 1024 + n0]) = pk;
            }
        }
    } else {
        // swapped: lane holds 4 consecutive features (quad*4+r) of token row+m16
        ushort* base  = (nbase >= 768) ? ko : qo;
        const int off = (nbase >= 768) ? 768 : 0;
        #pragma unroll
        for (int j = 0; j < 4; j++) {
            const int f0 = colbase + j * 16 + quad * 4 - off;
            const int h = f0 >> 6, d0 = f0 & 63;
            #pragma unroll
            for (int i = 0; i < 4; i++) {
                const int tok = mbase + wm * 64 + i * 16 + m16;
                const int b = tok >> 10, n = tok & 1023;
                ushort4 pk;
                pk.x = f2b(acc[i][j][0]); pk.y = f2b(acc[i][j][1]);
                pk.z = f2b(acc[i][j][2]); pk.w = f2b(acc[i][j][3]);
                *reinterpret_cast<ushort4*>(
                    &base[((size_t)(b * 12 + h) * 1024 + n) * 64 + d0]) = pk;
            }
        }
    }
}

// ---------------- k_proj: R8-baseline 128x128, BK=32, dbuf, f32+bias out ----------

__global__ __launch_bounds__(256, 2)
void k_proj(const ushort* __restrict__ A, const ushort* __restrict__ Bt,
            float* __restrict__ co, const float* __restrict__ bias,
            int N, int K) {
    __shared__ ushort As[2][128 * 32];
    __shared__ ushort Bs[2][128 * 32];
    const int id   = blockIdx.x;
    const int xcd  = id & 7;
    const int s    = id >> 3;
    const int by   = xcd * 8 + (s & 7);
    const int bx   = s >> 3;
    const int tid  = threadIdx.x;
    const int lane = tid & 63;
    const int w    = tid >> 6;
    const int wm   = w >> 1, wn = w & 1;
    const int m16  = lane & 15, quad = lane >> 4;
    const int mbase = by * 128, nbase = bx * 128;

    f32x4 acc[4][4];
    #pragma unroll
    for (int i = 0; i < 4; i++)
        #pragma unroll
        for (int j = 0; j < 4; j++) acc[i][j] = (f32x4){0.f, 0.f, 0.f, 0.f};

    const int rS = w * 32 + (lane >> 2);
    const int cS = (lane & 3) * 8;
    const int wOff0 = (w * 2 + 0) * 512;
    const int wOff1 = (w * 2 + 1) * 512;
    const ushort* gA0 = &A [(size_t)(mbase + rS)      * K + cS];
    const ushort* gA1 = &A [(size_t)(mbase + rS + 16) * K + cS];
    const ushort* gB0 = &Bt[(size_t)(nbase + rS)      * K + cS];
    const ushort* gB1 = &Bt[(size_t)(nbase + rS + 16) * K + cS];

    async_cp16(gA0, &As[0][wOff0]);
    async_cp16(gA1, &As[0][wOff1]);
    async_cp16(gB0, &Bs[0][wOff0]);
    async_cp16(gB1, &Bs[0][wOff1]);

    for (int kt = 0; kt < K; kt += 32) {
        const int cur = (kt >> 5) & 1, nxt = cur ^ 1;
        __syncthreads();
        if (kt + 32 < K) {
            async_cp16(gA0 + kt + 32, &As[nxt][wOff0]);
            async_cp16(gA1 + kt + 32, &As[nxt][wOff1]);
            async_cp16(gB0 + kt + 32, &Bs[nxt][wOff0]);
            async_cp16(gB1 + kt + 32, &Bs[nxt][wOff1]);
        }
        b16x8 af[4], bfr[4];
        #pragma unroll
        for (int i = 0; i < 4; i++)
            af[i] = *reinterpret_cast<const b16x8*>(&As[cur][(wm * 64 + i * 16 + m16) * 32 + quad * 8]);
        #pragma unroll
        for (int j = 0; j < 4; j++)
            bfr[j] = *reinterpret_cast<const b16x8*>(&Bs[cur][(wn * 64 + j * 16 + m16) * 32 + quad * 8]);
        #pragma unroll
        for (int i = 0; i < 4; i++)
            #pragma unroll
            for (int j = 0; j < 4; j++)
                acc[i][j] = __builtin_amdgcn_mfma_f32_16x16x32_bf16(bfr[j], af[i], acc[i][j], 0, 0, 0);
    }

    #pragma unroll
    for (int j = 0; j < 4; j++) {
        const int f0 = nbase + wn * 64 + j * 16 + quad * 4;
        #pragma unroll
        for (int i = 0; i < 4; i++) {
            const int tok = mbase + wm * 64 + i * 16 + m16;
            float4 val;
            val.x = acc[i][j][0] + bias[f0 + 0];
            val.y = acc[i][j][1] + bias[f0 + 1];
            val.z = acc[i][j][2] + bias[f0 + 2];
            val.w = acc[i][j][3] + bias[f0 + 3];
            *reinterpret_cast<float4*>(&co[(size_t)tok * N + f0]) = val;
        }
    }
}

// ---------------- attention: flash, LDS-staged K/V, Q-blocked x2 (unchanged) ----------

#define AP 72   // LDS row pitch (elements)

__global__ __launch_bounds__(256)
void k_attn(const ushort* __restrict__ qa, const ushort* __restrict__ ka,
            const ushort* __restrict__ vt, ushort* __restrict__ ao) {
    __shared__ ushort Ks[64 * AP];
    __shared__ ushort Vs[64 * AP];

    const int l    = blockIdx.x;               // 0..767
    const int xcd  = l & 7;
    const int g    = l >> 3;                   // 0..95
    const int head = (g % 12) * 8 + xcd;       // head%8 == xcd -> XCD locality
    const int qsup = g / 12;                   // 0..7 (128-row supertile)
    const int tid  = threadIdx.x;
    const int w    = tid >> 6;
    const int lane = tid & 63;
    const int n    = lane & 15;
    const int q    = lane >> 4;

    const ushort* qh = qa + (size_t)head * 65536;
    const ushort* kh = ka + (size_t)head * 65536;
    const ushort* vh = vt + (size_t)head * 65536;
    const int qrow0 = qsup * 128 + w * 32;

    b16x8 bq0[2], bq1[2];
    #pragma unroll
    for (int u = 0; u < 2; u++) {
        bq0[u] = *reinterpret_cast<const b16x8*>(&qh[(qrow0 + u * 16 + n) * 64 + q * 8]);
        bq1[u] = *reinterpret_cast<const b16x8*>(&qh[(qrow0 + u * 16 + n) * 64 + 32 + q * 8]);
    }

    const int kr0 = tid >> 3, kc0 = (tid & 7) * 8;
    const int kr1 = kr0 + 32, kc1 = kc0;

    int4 kg0, kg1, vg0, vg1;
    kg0 = *reinterpret_cast<const int4*>(&kh[(0 + kr0) * 64 + kc0]);
    kg1 = *reinterpret_cast<const int4*>(&kh[(0 + kr1) * 64 + kc1]);
    vg0 = *reinterpret_cast<const int4*>(&vh[kr0 * 1024 + 0 + kc0]);
    vg1 = *reinterpret_cast<const int4*>(&vh[kr1 * 1024 + 0 + kc1]);

    f32x4 o[2][4];
    #pragma unroll
    for (int u = 0; u < 2; u++)
        #pragma unroll
        for (int dt = 0; dt < 4; dt++) o[u][dt] = (f32x4){0, 0, 0, 0};
    float Lacc[2] = {0.f, 0.f};

    const float SC = 0.125f * 1.4426950408889634f;
    const int s0 = ((q & 1) * 2) * 16 + n;
    const int s1 = s0 + 16;
    const bool lowq = (q < 2);

    for (int m0 = 0; m0 < 1024; m0 += 64) {
        *reinterpret_cast<int4*>(&Ks[kr0 * AP + kc0]) = kg0;
        *reinterpret_cast<int4*>(&Ks[kr1 * AP + kc1]) = kg1;
        *reinterpret_cast<int4*>(&Vs[kr0 * AP + kc0]) = vg0;
        *reinterpret_cast<int4*>(&Vs[kr1 * AP + kc1]) = vg1;
        __syncthreads();

        if (m0 + 64 < 1024) {
            kg0 = *reinterpret_cast<const int4*>(&kh[(m0 + 64 + kr0) * 64 + kc0]);
            kg1 = *reinterpret_cast<const int4*>(&kh[(m0 + 64 + kr1) * 64 + kc1]);
            vg0 = *reinterpret_cast<const int4*>(&vh[kr0 * 1024 + m0 + 64 + kc0]);
            vg1 = *reinterpret_cast<const int4*>(&vh[kr1 * 1024 + m0 + 64 + kc1]);
        }

        #pragma unroll
        for (int mc = 0; mc < 2; mc++) {
            b16x8 ka0t[2], ka1t[2];
            #pragma unroll
            for (int t = 0; t < 2; t++) {
                ka0t[t] = *reinterpret_cast<const b16x8*>(&Ks[(mc * 32 + t * 16 + n) * AP + q * 8]);
                ka1t[t] = *reinterpret_cast<const b16x8*>(&Ks[(mc * 32 + t * 16 + n) * AP + 32 + q * 8]);
            }
            f32x4 st[2][2];
            #pragma unroll
            for (int u = 0; u < 2; u++)
                #pragma unroll
                for (int t = 0; t < 2; t++) {
                    st[u][t] = (f32x4){0, 0, 0, 0};
                    st[u][t] = __builtin_amdgcn_mfma_f32_16x16x32_bf16(ka0t[t], bq0[u], st[u][t], 0, 0, 0);
                    st[u][t] = __builtin_amdgcn_mfma_f32_16x16x32_bf16(ka1t[t], bq1[u], st[u][t], 0, 0, 0);
                }

            union { uint4 u4; b16x8 v; } bp[2];
            #pragma unroll
            for (int u = 0; u < 2; u++) {
                float p00 = __builtin_amdgcn_exp2f(st[u][0][0] * SC);
                float p01 = __builtin_amdgcn_exp2f(st[u][0][1] * SC);
                float p02 = __builtin_amdgcn_exp2f(st[u][0][2] * SC);
                float p03 = __builtin_amdgcn_exp2f(st[u][0][3] * SC);
                float p10 = __builtin_amdgcn_exp2f(st[u][1][0] * SC);
                float p11 = __builtin_amdgcn_exp2f(st[u][1][1] * SC);
                float p12 = __builtin_amdgcn_exp2f(st[u][1][2] * SC);
                float p13 = __builtin_amdgcn_exp2f(st[u][1][3] * SC);
                Lacc[u] += ((p00 + p01) + (p02 + p03)) + ((p10 + p11) + (p12 + p13));

                const uint pk00 = packbf(p00, p01), pk01 = packbf(p02, p03);
                const uint pk10 = packbf(p10, p11), pk11 = packbf(p12, p13);

                uint a, b, dw0, dw1, dw2, dw3;
                a = __shfl((int)pk00, s0); b = __shfl((int)pk10, s0); dw0 = lowq ? a : b;
                a = __shfl((int)pk01, s0); b = __shfl((int)pk11, s0); dw1 = lowq ? a : b;
                a = __shfl((int)pk00, s1); b = __shfl((int)pk10, s1); dw2 = lowq ? a : b;
                a = __shfl((int)pk01, s1); b = __shfl((int)pk11, s1); dw3 = lowq ? a : b;
                bp[u].u4 = (uint4){dw0, dw1, dw2, dw3};
            }

            #pragma unroll
            for (int dt = 0; dt < 4; dt++) {
                const b16x8 av = *reinterpret_cast<const b16x8*>(
                    &Vs[(dt * 16 + n) * AP + mc * 32 + q * 8]);
                #pragma unroll
                for (int u = 0; u < 2; u++)
                    o[u][dt] = __builtin_amdgcn_mfma_f32_16x16x32_bf16(av, bp[u].v, o[u][dt], 0, 0, 0);
            }
        }
        __syncthreads();
    }

    const int bb = head / 12, h = head - bb * 12;
    #pragma unroll
    for (int u = 0; u < 2; u++) {
        float L = Lacc[u];
        L += __shfl_xor(L, 16);
        L += __shfl_xor(L, 32);
        const float inv = 1.f / L;
        ushort* dst = ao + ((size_t)(bb * 1024 + qrow0 + u * 16 + n)) * 768 + h * 64 + q * 4;
        #pragma unroll
        for (int dt = 0; dt < 4; dt++) {
            ushort4 pk;
            pk.x = f2b(o[u][dt][0] * inv);
            pk.y = f2b(o[u][dt][1] * inv);
            pk.z = f2b(o[u][dt][2] * inv);
            pk.w = f2b(o[u][dt][3] * inv);
            *reinterpret_cast<ushort4*>(dst + dt * 16) = pk;
        }
    }
}

// ---------------- launch ----------------

extern "C" void kernel_launch(void* const* d_in, const int* in_sizes, int n_in,
                              void* d_out, int out_size, void* d_ws, size_t ws_size,
                              hipStream_t stream) {
    (void)in_sizes; (void)n_in; (void)out_size; (void)ws_size;
    const float* x     = (const float*)d_in[0];
    const float* Wqkv  = (const float*)d_in[4];
    const float* Wproj = (const float*)d_in[5];
    const float* bproj = (const float*)d_in[6];
    float* out = (float*)d_out;

    char* ws = (char*)d_ws;
    ushort* xb     = (ushort*)ws; ws += (size_t)8192 * 768 * 2;
    ushort* wqkvt  = (ushort*)ws; ws += (size_t)2304 * 768 * 2;
    ushort* wprojt = (ushort*)ws; ws += (size_t)768  * 768 * 2;
    ushort* qa     = (ushort*)ws; ws += (size_t)96 * 1024 * 64 * 2;
    ushort* ka     = (ushort*)ws; ws += (size_t)96 * 1024 * 64 * 2;
    ushort* vt     = (ushort*)ws; ws += (size_t)96 * 64 * 1024 * 2;
    ushort* ao     = (ushort*)ws; ws += (size_t)8192 * 768 * 2;

    static int attr_set = 0;
    if (!attr_set) {
        hipFuncSetAttribute((const void*)k_qkv,
                            hipFuncAttributeMaxDynamicSharedMemorySize, 98304);
        attr_set = 1;
    }

    k_prep<<<dim3(6720), dim3(256), 0, stream>>>(x, xb, Wqkv, wqkvt, Wproj, wprojt);
    k_qkv<<<dim3(576), dim3(512), 98304, stream>>>(xb, wqkvt, qa, ka, vt);
    k_attn<<<dim3(768), dim3(256), 0, stream>>>(qa, ka, vt, ao);
    k_proj<<<dim3(384), dim3(256), 0, stream>>>(ao, wprojt, out, bproj, 768, 768);
}